// Round 1
// baseline (1307.400 us; speedup 1.0000x reference)
//
#include <hip/hip_runtime.h>
#include <hip/hip_bf16.h>
#include <math.h>

// Problem constants (from reference): BN=2, L=1024, DM=1024, D_STATE=16,
// D_CONV=4, EXPAND=2, D_INNER=2048. M = BN*L = 2048.
#define BN_   2
#define L_    1024
#define DM_   1024
#define DS_   16
#define DI_   2048
#define M_    (BN_ * L_)

// ---------------------------------------------------------------------------
// Generic fp32 tiled GEMM:  C[M][N] = A[M][K] @ W[K][N] + bias[N]  (+ optional
// softplus). 64x64 tile, 256 threads, 4x4 micro-tile, K-tile 16.
// Requires M%64==0, N%64==0, K%16==0 (true for all three call sites).
// ---------------------------------------------------------------------------
__global__ __launch_bounds__(256) void gemm_bias(
    const float* __restrict__ A, const float* __restrict__ W,
    const float* __restrict__ bias, float* __restrict__ C,
    int M, int N, int K, int act)
{
    __shared__ float As[64][17];   // +1 pad breaks 4-way bank conflict on col reads
    __shared__ float Bs[16][64];

    const int tid = threadIdx.x;
    const int tx  = tid & 15;      // N dir
    const int ty  = tid >> 4;      // M dir
    const int row0 = blockIdx.y * 64;
    const int col0 = blockIdx.x * 64;

    // load-index decomposition
    const int lm  = tid >> 2;          // 0..63  (A row within tile)
    const int lk4 = (tid & 3) * 4;     // 0,4,8,12 (A k offset)
    const int lk  = tid >> 4;          // 0..15  (B k)
    const int ln4 = (tid & 15) * 4;    // B n offset

    float acc[4][4] = {};

    for (int kt = 0; kt < K; kt += 16) {
        float4 av = *(const float4*)(A + (size_t)(row0 + lm) * K + kt + lk4);
        As[lm][lk4 + 0] = av.x;
        As[lm][lk4 + 1] = av.y;
        As[lm][lk4 + 2] = av.z;
        As[lm][lk4 + 3] = av.w;
        float4 bv = *(const float4*)(W + (size_t)(kt + lk) * N + col0 + ln4);
        *(float4*)(&Bs[lk][ln4]) = bv;
        __syncthreads();

        #pragma unroll
        for (int kk = 0; kk < 16; ++kk) {
            float a[4], b[4];
            #pragma unroll
            for (int i = 0; i < 4; ++i) a[i] = As[ty * 4 + i][kk];
            #pragma unroll
            for (int j = 0; j < 4; ++j) b[j] = Bs[kk][tx * 4 + j];
            #pragma unroll
            for (int i = 0; i < 4; ++i)
                #pragma unroll
                for (int j = 0; j < 4; ++j)
                    acc[i][j] = fmaf(a[i], b[j], acc[i][j]);
        }
        __syncthreads();
    }

    #pragma unroll
    for (int i = 0; i < 4; ++i) {
        const int r = row0 + ty * 4 + i;
        #pragma unroll
        for (int j = 0; j < 4; ++j) {
            const int c = col0 + tx * 4 + j;
            float v = acc[i][j] + bias[c];
            if (act == 1) {                       // softplus
                v = (v > 20.0f) ? v : log1pf(__expf(v));
            }
            C[(size_t)r * N + c] = v;
        }
    }
}

// ---------------------------------------------------------------------------
// Depthwise conv (window 4, SAME padding: taps t-1..t+2) + bias + SiLU.
// x_z is the first DI_ columns of xp ([M][2*DI]).
// ---------------------------------------------------------------------------
__global__ __launch_bounds__(256) void conv_silu(
    const float* __restrict__ xp, const float* __restrict__ cw,
    const float* __restrict__ cb, float* __restrict__ xc)
{
    const int idx = blockIdx.x * 256 + threadIdx.x;   // over BN*L*DI
    if (idx >= BN_ * L_ * DI_) return;
    const int d = idx & (DI_ - 1);
    const int t = (idx / DI_) & (L_ - 1);
    const int b = idx / (DI_ * L_);

    float acc = cb[d];
    #pragma unroll
    for (int w = 0; w < 4; ++w) {
        const int tt = t + w - 1;
        if (tt >= 0 && tt < L_)
            acc = fmaf(xp[((size_t)(b * L_ + tt)) * (2 * DI_) + d], cw[w * DI_ + d], acc);
    }
    xc[idx] = acc / (1.0f + __expf(-acc));            // silu
}

// ---------------------------------------------------------------------------
// B / C projections: Bm[r][s] = x_conv[r][:] @ B_w[:,s] + B_b[s] (same for C).
// One block (256 threads) per row; wave shuffle reduce then LDS combine.
// ---------------------------------------------------------------------------
__global__ __launch_bounds__(256) void bc_proj(
    const float* __restrict__ xc,
    const float* __restrict__ Bw, const float* __restrict__ Bb,
    const float* __restrict__ Cw, const float* __restrict__ Cb,
    float* __restrict__ Bm, float* __restrict__ Cm)
{
    const int r = blockIdx.x;
    const int tid = threadIdx.x;

    float accB[DS_] = {};
    float accC[DS_] = {};
    for (int k = tid; k < DI_; k += 256) {
        const float xv = xc[(size_t)r * DI_ + k];
        #pragma unroll
        for (int s = 0; s < DS_; ++s) {
            accB[s] = fmaf(xv, Bw[k * DS_ + s], accB[s]);
            accC[s] = fmaf(xv, Cw[k * DS_ + s], accC[s]);
        }
    }
    #pragma unroll
    for (int s = 0; s < DS_; ++s) {
        #pragma unroll
        for (int off = 32; off > 0; off >>= 1) {
            accB[s] += __shfl_down(accB[s], off);
            accC[s] += __shfl_down(accC[s], off);
        }
    }
    __shared__ float redB[4][DS_], redC[4][DS_];
    const int wave = tid >> 6, lane = tid & 63;
    if (lane == 0) {
        #pragma unroll
        for (int s = 0; s < DS_; ++s) { redB[wave][s] = accB[s]; redC[wave][s] = accC[s]; }
    }
    __syncthreads();
    if (tid < DS_) {
        Bm[r * DS_ + tid] = redB[0][tid] + redB[1][tid] + redB[2][tid] + redB[3][tid] + Bb[tid];
        Cm[r * DS_ + tid] = redC[0][tid] + redC[1][tid] + redC[2][tid] + redC[3][tid] + Cb[tid];
    }
}

// ---------------------------------------------------------------------------
// Selective scan, one (batch, channel) per lane, sequential over L. Fuses the
// +x_conv*Dp skip and the silu(gate) multiply (epilogue of the reference).
// 64-thread blocks -> 64 independent waves spread over CUs.
// ---------------------------------------------------------------------------
__global__ __launch_bounds__(64) void scan_fused(
    const float* __restrict__ dt, const float* __restrict__ xc,
    const float* __restrict__ xp,                    // gate = xp[:, DI_:2*DI_]
    const float* __restrict__ Bm, const float* __restrict__ Cm,
    const float* __restrict__ A, const float* __restrict__ Dp,
    float* __restrict__ yg)
{
    const int idx = blockIdx.x * 64 + threadIdx.x;   // over BN*DI
    const int d = idx & (DI_ - 1);
    const int b = idx / DI_;

    float a[DS_];
    #pragma unroll
    for (int q = 0; q < 4; ++q) {
        float4 v = *(const float4*)(A + (size_t)d * DS_ + q * 4);
        a[q * 4 + 0] = v.x; a[q * 4 + 1] = v.y; a[q * 4 + 2] = v.z; a[q * 4 + 3] = v.w;
    }
    const float dp = Dp[d];

    float h[DS_] = {};
    for (int t = 0; t < L_; ++t) {
        const size_t r = (size_t)b * L_ + t;
        const float dtv = dt[r * DI_ + d];
        const float xcv = xc[r * DI_ + d];
        const float gv  = xp[r * (2 * DI_) + DI_ + d];

        float bmv[DS_], cmv[DS_];
        #pragma unroll
        for (int q = 0; q < 4; ++q) {
            float4 vb = *(const float4*)(Bm + r * DS_ + q * 4);
            float4 vc = *(const float4*)(Cm + r * DS_ + q * 4);
            bmv[q*4+0] = vb.x; bmv[q*4+1] = vb.y; bmv[q*4+2] = vb.z; bmv[q*4+3] = vb.w;
            cmv[q*4+0] = vc.x; cmv[q*4+1] = vc.y; cmv[q*4+2] = vc.z; cmv[q*4+3] = vc.w;
        }

        float y = 0.0f;
        const float dx = dtv * xcv;
        #pragma unroll
        for (int s = 0; s < DS_; ++s) {
            const float dA = __expf(dtv * a[s]);
            h[s] = fmaf(dA, h[s], dx * bmv[s]);
            y = fmaf(h[s], cmv[s], y);
        }
        y = fmaf(xcv, dp, y);
        yg[r * DI_ + d] = y * (gv / (1.0f + __expf(-gv)));
    }
}

// ---------------------------------------------------------------------------
extern "C" void kernel_launch(void* const* d_in, const int* in_sizes, int n_in,
                              void* d_out, int out_size, void* d_ws, size_t ws_size,
                              hipStream_t stream)
{
    const float* x      = (const float*)d_in[0];
    const float* in_w   = (const float*)d_in[1];
    const float* in_b   = (const float*)d_in[2];
    const float* conv_w = (const float*)d_in[3];
    const float* conv_b = (const float*)d_in[4];
    const float* A      = (const float*)d_in[5];
    const float* Dp     = (const float*)d_in[6];
    const float* B_w    = (const float*)d_in[7];
    const float* B_b    = (const float*)d_in[8];
    const float* C_w    = (const float*)d_in[9];
    const float* C_b    = (const float*)d_in[10];
    const float* dt_w   = (const float*)d_in[11];
    const float* dt_b   = (const float*)d_in[12];
    const float* out_w  = (const float*)d_in[13];
    const float* out_b  = (const float*)d_in[14];
    float* out = (float*)d_out;

    // workspace layout (fp32)
    float* xp  = (float*)d_ws;            // [M][2*DI]   32 MB
    float* xc  = xp  + (size_t)M_ * 2 * DI_; // [M][DI]  16 MB
    float* dtb = xc  + (size_t)M_ * DI_;     // [M][DI]  16 MB
    float* yg  = dtb + (size_t)M_ * DI_;     // [M][DI]  16 MB
    float* Bm  = yg  + (size_t)M_ * DI_;     // [M][16]
    float* Cm  = Bm  + (size_t)M_ * DS_;     // [M][16]

    // 1) xp = x @ in_w + in_b        (M=2048, N=4096, K=1024)
    gemm_bias<<<dim3(4096 / 64, M_ / 64), 256, 0, stream>>>(
        x, in_w, in_b, xp, M_, 2 * DI_, DM_, 0);

    // 2) depthwise conv + silu
    conv_silu<<<(BN_ * L_ * DI_) / 256, 256, 0, stream>>>(xp, conv_w, conv_b, xc);

    // 3) Bm, Cm projections (N=16 each)
    bc_proj<<<M_, 256, 0, stream>>>(xc, B_w, B_b, C_w, C_b, Bm, Cm);

    // 4) dt = softplus(x_conv @ dt_w + dt_b)   (M=2048, N=2048, K=2048)
    gemm_bias<<<dim3(DI_ / 64, M_ / 64), 256, 0, stream>>>(
        xc, dt_w, dt_b, dtb, M_, DI_, DI_, 1);

    // 5) scan + skip + gate  -> yg
    scan_fused<<<(BN_ * DI_) / 64, 64, 0, stream>>>(
        dtb, xc, xp, Bm, Cm, A, Dp, yg);

    // 6) out = yg @ out_w + out_b    (M=2048, N=1024, K=2048)
    gemm_bias<<<dim3(DM_ / 64, M_ / 64), 256, 0, stream>>>(
        yg, out_w, out_b, out, M_, DM_, DI_, 0);
}

// Round 2
// 939.686 us; speedup vs baseline: 1.3913x; 1.3913x over previous
//
#include <hip/hip_runtime.h>
#include <hip/hip_bf16.h>
#include <math.h>

// Problem constants: BN=2, L=1024, DM=1024, D_STATE=16, D_CONV=4, EXPAND=2,
// D_INNER=2048. M = BN*L = 2048.
#define BN_   2
#define L_    1024
#define DM_   1024
#define DS_   16
#define DI_   2048
#define M_    (BN_ * L_)

// ---------------------------------------------------------------------------
// Generic fp32 tiled GEMM:  C[M][N] = A[M][K] @ W[K][N] + bias[N]  (+ optional
// softplus). 64x64 tile, 256 threads, 4x4 micro-tile, K-tile 16.
// ---------------------------------------------------------------------------
__global__ __launch_bounds__(256) void gemm_bias(
    const float* __restrict__ A, const float* __restrict__ W,
    const float* __restrict__ bias, float* __restrict__ C,
    int M, int N, int K, int act)
{
    __shared__ float As[64][17];
    __shared__ float Bs[16][64];

    const int tid = threadIdx.x;
    const int tx  = tid & 15;
    const int ty  = tid >> 4;
    const int row0 = blockIdx.y * 64;
    const int col0 = blockIdx.x * 64;

    const int lm  = tid >> 2;
    const int lk4 = (tid & 3) * 4;
    const int lk  = tid >> 4;
    const int ln4 = (tid & 15) * 4;

    float acc[4][4] = {};

    for (int kt = 0; kt < K; kt += 16) {
        float4 av = *(const float4*)(A + (size_t)(row0 + lm) * K + kt + lk4);
        As[lm][lk4 + 0] = av.x;
        As[lm][lk4 + 1] = av.y;
        As[lm][lk4 + 2] = av.z;
        As[lm][lk4 + 3] = av.w;
        float4 bv = *(const float4*)(W + (size_t)(kt + lk) * N + col0 + ln4);
        *(float4*)(&Bs[lk][ln4]) = bv;
        __syncthreads();

        #pragma unroll
        for (int kk = 0; kk < 16; ++kk) {
            float a[4], b[4];
            #pragma unroll
            for (int i = 0; i < 4; ++i) a[i] = As[ty * 4 + i][kk];
            #pragma unroll
            for (int j = 0; j < 4; ++j) b[j] = Bs[kk][tx * 4 + j];
            #pragma unroll
            for (int i = 0; i < 4; ++i)
                #pragma unroll
                for (int j = 0; j < 4; ++j)
                    acc[i][j] = fmaf(a[i], b[j], acc[i][j]);
        }
        __syncthreads();
    }

    #pragma unroll
    for (int i = 0; i < 4; ++i) {
        const int r = row0 + ty * 4 + i;
        #pragma unroll
        for (int j = 0; j < 4; ++j) {
            const int c = col0 + tx * 4 + j;
            float v = acc[i][j] + bias[c];
            if (act == 1) {
                v = (v > 20.0f) ? v : log1pf(__expf(v));
            }
            C[(size_t)r * N + c] = v;
        }
    }
}

// ---------------------------------------------------------------------------
// Depthwise conv (window 4, SAME: taps t-1..t+2) + bias + SiLU.
// ---------------------------------------------------------------------------
__global__ __launch_bounds__(256) void conv_silu(
    const float* __restrict__ xp, const float* __restrict__ cw,
    const float* __restrict__ cb, float* __restrict__ xc)
{
    const int idx = blockIdx.x * 256 + threadIdx.x;
    if (idx >= BN_ * L_ * DI_) return;
    const int d = idx & (DI_ - 1);
    const int t = (idx / DI_) & (L_ - 1);
    const int b = idx / (DI_ * L_);

    float acc = cb[d];
    #pragma unroll
    for (int w = 0; w < 4; ++w) {
        const int tt = t + w - 1;
        if (tt >= 0 && tt < L_)
            acc = fmaf(xp[((size_t)(b * L_ + tt)) * (2 * DI_) + d], cw[w * DI_ + d], acc);
    }
    xc[idx] = acc / (1.0f + __expf(-acc));
}

// ---------------------------------------------------------------------------
// B / C projections.
// ---------------------------------------------------------------------------
__global__ __launch_bounds__(256) void bc_proj(
    const float* __restrict__ xc,
    const float* __restrict__ Bw, const float* __restrict__ Bb,
    const float* __restrict__ Cw, const float* __restrict__ Cb,
    float* __restrict__ Bm, float* __restrict__ Cm)
{
    const int r = blockIdx.x;
    const int tid = threadIdx.x;

    float accB[DS_] = {};
    float accC[DS_] = {};
    for (int k = tid; k < DI_; k += 256) {
        const float xv = xc[(size_t)r * DI_ + k];
        #pragma unroll
        for (int s = 0; s < DS_; ++s) {
            accB[s] = fmaf(xv, Bw[k * DS_ + s], accB[s]);
            accC[s] = fmaf(xv, Cw[k * DS_ + s], accC[s]);
        }
    }
    #pragma unroll
    for (int s = 0; s < DS_; ++s) {
        #pragma unroll
        for (int off = 32; off > 0; off >>= 1) {
            accB[s] += __shfl_down(accB[s], off);
            accC[s] += __shfl_down(accC[s], off);
        }
    }
    __shared__ float redB[4][DS_], redC[4][DS_];
    const int wave = tid >> 6, lane = tid & 63;
    if (lane == 0) {
        #pragma unroll
        for (int s = 0; s < DS_; ++s) { redB[wave][s] = accB[s]; redC[wave][s] = accC[s]; }
    }
    __syncthreads();
    if (tid < DS_) {
        Bm[r * DS_ + tid] = redB[0][tid] + redB[1][tid] + redB[2][tid] + redB[3][tid] + Bb[tid];
        Cm[r * DS_ + tid] = redC[0][tid] + redC[1][tid] + redC[2][tid] + redC[3][tid] + Cb[tid];
    }
}

// ---------------------------------------------------------------------------
// Selective scan, restructured for latency hiding:
//   - one STATE per lane: 16 lanes per channel, 16 channels per 256-thr block
//   - grid (DI/16, BN) = 256 blocks = 1024 waves (vs 64 before)
//   - all per-t operands staged through double-buffered LDS in 64-step chunks
//     with coalesced float4 loads; outputs collected in LDS, written coalesced
//   - loop-carried chain per step: one exp + one fmaf (off-LDS, pipelined)
// Fuses +x_conv*Dp and *silu(gate).
// ---------------------------------------------------------------------------
#define CH_ 16    // channels per block
#define TB_ 64    // timesteps per chunk
#define NCHUNK_ (L_ / TB_)

__global__ __launch_bounds__(256) void scan_fused(
    const float* __restrict__ dt, const float* __restrict__ xc,
    const float* __restrict__ xp,                    // gate = xp[:, DI_:2*DI_]
    const float* __restrict__ Bm, const float* __restrict__ Cm,
    const float* __restrict__ A, const float* __restrict__ Dp,
    float* __restrict__ yg)
{
    const int tid = threadIdx.x;
    const int s   = tid & 15;        // state index
    const int c   = tid >> 4;        // channel within block (0..15)
    const int d0  = blockIdx.x * CH_;
    const int b   = blockIdx.y;
    const int d   = d0 + c;

    __shared__ float s_dt[2][TB_][CH_];
    __shared__ float s_xc[2][TB_][CH_];
    __shared__ float s_gv[2][TB_][CH_];
    __shared__ float s_Bm[2][TB_][DS_];
    __shared__ float s_Cm[2][TB_][DS_];
    __shared__ float s_y [TB_][CH_];

    // staging decomposition: 256 threads cover 64 rows x 16 cols via float4
    const int rt = tid >> 2;          // row in chunk (0..63)
    const int q  = (tid & 3) * 4;     // col offset {0,4,8,12}

    #define STAGE(bufi, t0) { \
        const size_t rr = (size_t)(b * L_ + (t0) + rt); \
        *(float4*)&s_dt[bufi][rt][q] = *(const float4*)(dt + rr * DI_ + d0 + q); \
        *(float4*)&s_xc[bufi][rt][q] = *(const float4*)(xc + rr * DI_ + d0 + q); \
        *(float4*)&s_gv[bufi][rt][q] = *(const float4*)(xp + rr * 2 * DI_ + DI_ + d0 + q); \
        *(float4*)&s_Bm[bufi][rt][q] = *(const float4*)(Bm + rr * DS_ + q); \
        *(float4*)&s_Cm[bufi][rt][q] = *(const float4*)(Cm + rr * DS_ + q); \
    }

    const float a_s = A[(size_t)d * DS_ + s];
    const float dp  = Dp[d];

    float h = 0.0f;
    int buf = 0;

    STAGE(0, 0);

    for (int chunk = 0; chunk < NCHUNK_; ++chunk) {
        __syncthreads();                          // stage(buf) visible; s_y free
        if (chunk + 1 < NCHUNK_) STAGE(buf ^ 1, (chunk + 1) * TB_);

        #pragma unroll 4
        for (int t = 0; t < TB_; ++t) {
            const float dtv = s_dt[buf][t][c];
            const float xcv = s_xc[buf][t][c];
            const float bm  = s_Bm[buf][t][s];
            const float cm  = s_Cm[buf][t][s];
            const float dA  = __expf(dtv * a_s);
            h = fmaf(dA, h, dtv * xcv * bm);
            float y = h * cm;
            y += __shfl_xor(y, 8);
            y += __shfl_xor(y, 4);
            y += __shfl_xor(y, 2);
            y += __shfl_xor(y, 1);
            if (s == 0) {
                const float gv = s_gv[buf][t][c];
                s_y[t][c] = fmaf(xcv, dp, y) * (gv / (1.0f + __expf(-gv)));
            }
        }

        __syncthreads();                          // s_y complete
        {
            const size_t rr = (size_t)(b * L_ + chunk * TB_ + rt);
            *(float4*)(yg + rr * DI_ + d0 + q) = *(float4*)&s_y[rt][q];
        }
        buf ^= 1;
    }
    #undef STAGE
}

// ---------------------------------------------------------------------------
extern "C" void kernel_launch(void* const* d_in, const int* in_sizes, int n_in,
                              void* d_out, int out_size, void* d_ws, size_t ws_size,
                              hipStream_t stream)
{
    const float* x      = (const float*)d_in[0];
    const float* in_w   = (const float*)d_in[1];
    const float* in_b   = (const float*)d_in[2];
    const float* conv_w = (const float*)d_in[3];
    const float* conv_b = (const float*)d_in[4];
    const float* A      = (const float*)d_in[5];
    const float* Dp     = (const float*)d_in[6];
    const float* B_w    = (const float*)d_in[7];
    const float* B_b    = (const float*)d_in[8];
    const float* C_w    = (const float*)d_in[9];
    const float* C_b    = (const float*)d_in[10];
    const float* dt_w   = (const float*)d_in[11];
    const float* dt_b   = (const float*)d_in[12];
    const float* out_w  = (const float*)d_in[13];
    const float* out_b  = (const float*)d_in[14];
    float* out = (float*)d_out;

    // workspace layout (fp32)
    float* xp  = (float*)d_ws;               // [M][2*DI]
    float* xc  = xp  + (size_t)M_ * 2 * DI_; // [M][DI]
    float* dtb = xc  + (size_t)M_ * DI_;     // [M][DI]
    float* yg  = dtb + (size_t)M_ * DI_;     // [M][DI]
    float* Bm  = yg  + (size_t)M_ * DI_;     // [M][16]
    float* Cm  = Bm  + (size_t)M_ * DS_;     // [M][16]

    // 1) xp = x @ in_w + in_b        (M=2048, N=4096, K=1024)
    gemm_bias<<<dim3(4096 / 64, M_ / 64), 256, 0, stream>>>(
        x, in_w, in_b, xp, M_, 2 * DI_, DM_, 0);

    // 2) depthwise conv + silu
    conv_silu<<<(BN_ * L_ * DI_) / 256, 256, 0, stream>>>(xp, conv_w, conv_b, xc);

    // 3) Bm, Cm projections
    bc_proj<<<M_, 256, 0, stream>>>(xc, B_w, B_b, C_w, C_b, Bm, Cm);

    // 4) dt = softplus(x_conv @ dt_w + dt_b)   (M=2048, N=2048, K=2048)
    gemm_bias<<<dim3(DI_ / 64, M_ / 64), 256, 0, stream>>>(
        xc, dt_w, dt_b, dtb, M_, DI_, DI_, 1);

    // 5) scan + skip + gate  -> yg
    scan_fused<<<dim3(DI_ / CH_, BN_), 256, 0, stream>>>(
        dtb, xc, xp, Bm, Cm, A, Dp, yg);

    // 6) out = yg @ out_w + out_b    (M=2048, N=1024, K=2048)
    gemm_bias<<<dim3(DM_ / 64, M_ / 64), 256, 0, stream>>>(
        yg, out_w, out_b, out, M_, DM_, DI_, 0);
}

// Round 3
// 475.311 us; speedup vs baseline: 2.7506x; 1.9770x over previous
//
#include <hip/hip_runtime.h>
#include <hip/hip_bf16.h>
#include <math.h>

// Problem constants: BN=2, L=1024, DM=1024, D_STATE=16, D_CONV=4, EXPAND=2,
// D_INNER=2048. M = BN*L = 2048.
#define BN_   2
#define L_    1024
#define DM_   1024
#define DS_   16
#define DI_   2048
#define M_    (BN_ * L_)

typedef __attribute__((ext_vector_type(8))) short short8;
typedef __attribute__((ext_vector_type(4))) float f32x4;

__device__ __forceinline__ unsigned short f2b(float f) {
    union { float f; unsigned u; } x; x.f = f;
    unsigned r = x.u + 0x7fffu + ((x.u >> 16) & 1u);   // RNE
    return (unsigned short)(r >> 16);
}

__device__ __forceinline__ void gload_lds16(const unsigned short* g, unsigned short* l) {
    __builtin_amdgcn_global_load_lds(
        (const __attribute__((address_space(1))) void*)g,
        (__attribute__((address_space(3))) void*)l, 16, 0, 0);
}

// ---------------------------------------------------------------------------
// elementwise fp32 -> bf16 cast (n multiple of 4)
// ---------------------------------------------------------------------------
__global__ __launch_bounds__(256) void cast_bf16(
    const float* __restrict__ in, unsigned short* __restrict__ out, int n)
{
    const int i = (blockIdx.x * 256 + threadIdx.x) * 4;
    if (i >= n) return;
    float4 v = *(const float4*)(in + i);
    ushort4 o; o.x = f2b(v.x); o.y = f2b(v.y); o.z = f2b(v.z); o.w = f2b(v.w);
    *(ushort4*)(out + i) = o;
}

// ---------------------------------------------------------------------------
// transpose + cast: in fp32 [R][C] -> out bf16 [C][R].  R,C multiples of 32.
// ---------------------------------------------------------------------------
__global__ __launch_bounds__(256) void transpose_cast(
    const float* __restrict__ in, unsigned short* __restrict__ out, int R, int C)
{
    __shared__ float t[32][33];
    const int bx = blockIdx.x * 32;   // C dir
    const int by = blockIdx.y * 32;   // R dir
    const int tx = threadIdx.x & 31;
    const int ty = (threadIdx.x >> 5) * 4;
    #pragma unroll
    for (int j = 0; j < 4; ++j)
        t[ty + j][tx] = in[(size_t)(by + ty + j) * C + bx + tx];
    __syncthreads();
    #pragma unroll
    for (int j = 0; j < 4; ++j)
        out[(size_t)(bx + ty + j) * R + by + tx] = f2b(t[tx][ty + j]);
}

// ---------------------------------------------------------------------------
// bf16 MFMA GEMM (m97 structure): C[M][N] = A[M][K] @ Bt[N][K]^T + bias.
// 128x128 tile, BK=64, 4 waves (2x2), each wave 64x64 = 4x4 frags of 16x16x32.
// act==1 -> softplus. fp32 accumulate, fp32 output.
// M%128==0, N%128==0, K%64==0.
// ---------------------------------------------------------------------------
__global__ __launch_bounds__(256) void gemm_mfma(
    const unsigned short* __restrict__ A,   // [M][K] bf16
    const unsigned short* __restrict__ Bt,  // [N][K] bf16
    const float* __restrict__ bias,
    float* __restrict__ C,
    int M, int N, int K, int act)
{
    __shared__ unsigned short Asl[128 * 64];
    __shared__ unsigned short Bsl[128 * 64];

    const int tid  = threadIdx.x;
    const int wave = tid >> 6;
    const int lane = tid & 63;
    const int row0 = blockIdx.y * 128;
    const int col0 = blockIdx.x * 128;
    const int wr   = (wave >> 1) * 64;    // wave row offset within tile
    const int wc   = (wave & 1) * 64;     // wave col offset

    const int srow = lane >> 3;           // staging: row within 8-row chunk
    const int scol = (lane & 7) * 8;      // staging: element col (8 bf16 = 16B)

    f32x4 acc[4][4];
    #pragma unroll
    for (int m = 0; m < 4; ++m)
        #pragma unroll
        for (int n = 0; n < 4; ++n)
            acc[m][n] = (f32x4){0.f, 0.f, 0.f, 0.f};

    for (int kt = 0; kt < K; kt += 64) {
        #pragma unroll
        for (int i = 0; i < 4; ++i) {
            const int chunk = wave * 4 + i;              // 0..15, 8 rows each
            gload_lds16(A  + (size_t)(row0 + chunk * 8 + srow) * K + kt + scol,
                        &Asl[chunk * 512]);
            gload_lds16(Bt + (size_t)(col0 + chunk * 8 + srow) * K + kt + scol,
                        &Bsl[chunk * 512]);
        }
        __syncthreads();   // drains vmcnt(0): staged tile visible

        short8 af[4][2], bf[4][2];
        #pragma unroll
        for (int m = 0; m < 4; ++m)
            #pragma unroll
            for (int kk = 0; kk < 2; ++kk)
                af[m][kk] = *(const short8*)
                    &Asl[(wr + m * 16 + (lane & 15)) * 64 + kk * 32 + (lane >> 4) * 8];
        #pragma unroll
        for (int n = 0; n < 4; ++n)
            #pragma unroll
            for (int kk = 0; kk < 2; ++kk)
                bf[n][kk] = *(const short8*)
                    &Bsl[(wc + n * 16 + (lane & 15)) * 64 + kk * 32 + (lane >> 4) * 8];

        #pragma unroll
        for (int m = 0; m < 4; ++m)
            #pragma unroll
            for (int n = 0; n < 4; ++n) {
                acc[m][n] = __builtin_amdgcn_mfma_f32_16x16x32_bf16(
                    af[m][0], bf[n][0], acc[m][n], 0, 0, 0);
                acc[m][n] = __builtin_amdgcn_mfma_f32_16x16x32_bf16(
                    af[m][1], bf[n][1], acc[m][n], 0, 0, 0);
            }
        __syncthreads();   // tile consumed, safe to restage
    }

    // epilogue: C/D layout col=lane&15, row=(lane>>4)*4+j  [m89/m91 verified]
    const int crow = (lane >> 4) * 4;
    const int ccol = lane & 15;
    #pragma unroll
    for (int m = 0; m < 4; ++m)
        #pragma unroll
        for (int n = 0; n < 4; ++n) {
            const int c = col0 + wc + n * 16 + ccol;
            const float bv = bias[c];
            #pragma unroll
            for (int j = 0; j < 4; ++j) {
                const int r = row0 + wr + m * 16 + crow + j;
                float v = acc[m][n][j] + bv;
                if (act == 1) v = (v > 20.0f) ? v : log1pf(__expf(v));
                C[(size_t)r * N + c] = v;
            }
        }
}

// ---------------------------------------------------------------------------
// Depthwise conv (window 4, SAME: taps t-1..t+2) + bias + SiLU.
// Writes fp32 xc (for scan / bc_proj) and bf16 xcb (for dt GEMM).
// ---------------------------------------------------------------------------
__global__ __launch_bounds__(256) void conv_silu(
    const float* __restrict__ xp, const float* __restrict__ cw,
    const float* __restrict__ cb, float* __restrict__ xc,
    unsigned short* __restrict__ xcb)
{
    const int idx = blockIdx.x * 256 + threadIdx.x;
    if (idx >= BN_ * L_ * DI_) return;
    const int d = idx & (DI_ - 1);
    const int t = (idx / DI_) & (L_ - 1);
    const int b = idx / (DI_ * L_);

    float acc = cb[d];
    #pragma unroll
    for (int w = 0; w < 4; ++w) {
        const int tt = t + w - 1;
        if (tt >= 0 && tt < L_)
            acc = fmaf(xp[((size_t)(b * L_ + tt)) * (2 * DI_) + d], cw[w * DI_ + d], acc);
    }
    const float s = acc / (1.0f + __expf(-acc));
    xc[idx]  = s;
    xcb[idx] = f2b(s);
}

// ---------------------------------------------------------------------------
// B / C projections (N=16 each), fp32.
// ---------------------------------------------------------------------------
__global__ __launch_bounds__(256) void bc_proj(
    const float* __restrict__ xc,
    const float* __restrict__ Bw, const float* __restrict__ Bb,
    const float* __restrict__ Cw, const float* __restrict__ Cb,
    float* __restrict__ Bm, float* __restrict__ Cm)
{
    const int r = blockIdx.x;
    const int tid = threadIdx.x;

    float accB[DS_] = {};
    float accC[DS_] = {};
    for (int k = tid; k < DI_; k += 256) {
        const float xv = xc[(size_t)r * DI_ + k];
        #pragma unroll
        for (int s = 0; s < DS_; ++s) {
            accB[s] = fmaf(xv, Bw[k * DS_ + s], accB[s]);
            accC[s] = fmaf(xv, Cw[k * DS_ + s], accC[s]);
        }
    }
    #pragma unroll
    for (int s = 0; s < DS_; ++s) {
        #pragma unroll
        for (int off = 32; off > 0; off >>= 1) {
            accB[s] += __shfl_down(accB[s], off);
            accC[s] += __shfl_down(accC[s], off);
        }
    }
    __shared__ float redB[4][DS_], redC[4][DS_];
    const int wave = tid >> 6, lane = tid & 63;
    if (lane == 0) {
        #pragma unroll
        for (int s = 0; s < DS_; ++s) { redB[wave][s] = accB[s]; redC[wave][s] = accC[s]; }
    }
    __syncthreads();
    if (tid < DS_) {
        Bm[r * DS_ + tid] = redB[0][tid] + redB[1][tid] + redB[2][tid] + redB[3][tid] + Bb[tid];
        Cm[r * DS_ + tid] = redC[0][tid] + redC[1][tid] + redC[2][tid] + redC[3][tid] + Cb[tid];
    }
}

// ---------------------------------------------------------------------------
// Selective scan (one state per lane, LDS-staged chunks). Output bf16.
// ---------------------------------------------------------------------------
#define CH_ 16
#define TB_ 64
#define NCHUNK_ (L_ / TB_)

__global__ __launch_bounds__(256) void scan_fused(
    const float* __restrict__ dt, const float* __restrict__ xc,
    const float* __restrict__ xp,                    // gate = xp[:, DI_:2*DI_]
    const float* __restrict__ Bm, const float* __restrict__ Cm,
    const float* __restrict__ A, const float* __restrict__ Dp,
    unsigned short* __restrict__ ygb)
{
    const int tid = threadIdx.x;
    const int s   = tid & 15;
    const int c   = tid >> 4;
    const int d0  = blockIdx.x * CH_;
    const int b   = blockIdx.y;
    const int d   = d0 + c;

    __shared__ float s_dt[2][TB_][CH_];
    __shared__ float s_xc[2][TB_][CH_];
    __shared__ float s_gv[2][TB_][CH_];
    __shared__ float s_Bm[2][TB_][DS_];
    __shared__ float s_Cm[2][TB_][DS_];
    __shared__ float s_y [TB_][CH_];

    const int rt = tid >> 2;
    const int q  = (tid & 3) * 4;

    #define STAGE(bufi, t0) { \
        const size_t rr = (size_t)(b * L_ + (t0) + rt); \
        *(float4*)&s_dt[bufi][rt][q] = *(const float4*)(dt + rr * DI_ + d0 + q); \
        *(float4*)&s_xc[bufi][rt][q] = *(const float4*)(xc + rr * DI_ + d0 + q); \
        *(float4*)&s_gv[bufi][rt][q] = *(const float4*)(xp + rr * 2 * DI_ + DI_ + d0 + q); \
        *(float4*)&s_Bm[bufi][rt][q] = *(const float4*)(Bm + rr * DS_ + q); \
        *(float4*)&s_Cm[bufi][rt][q] = *(const float4*)(Cm + rr * DS_ + q); \
    }

    const float a_s = A[(size_t)d * DS_ + s];
    const float dp  = Dp[d];

    float h = 0.0f;
    int buf = 0;

    STAGE(0, 0);

    for (int chunk = 0; chunk < NCHUNK_; ++chunk) {
        __syncthreads();
        if (chunk + 1 < NCHUNK_) STAGE(buf ^ 1, (chunk + 1) * TB_);

        #pragma unroll 4
        for (int t = 0; t < TB_; ++t) {
            const float dtv = s_dt[buf][t][c];
            const float xcv = s_xc[buf][t][c];
            const float bm  = s_Bm[buf][t][s];
            const float cm  = s_Cm[buf][t][s];
            const float dA  = __expf(dtv * a_s);
            h = fmaf(dA, h, dtv * xcv * bm);
            float y = h * cm;
            y += __shfl_xor(y, 8);
            y += __shfl_xor(y, 4);
            y += __shfl_xor(y, 2);
            y += __shfl_xor(y, 1);
            if (s == 0) {
                const float gv = s_gv[buf][t][c];
                s_y[t][c] = fmaf(xcv, dp, y) * (gv / (1.0f + __expf(-gv)));
            }
        }

        __syncthreads();
        {
            const size_t rr = (size_t)(b * L_ + chunk * TB_ + rt);
            float4 v = *(float4*)&s_y[rt][q];
            ushort4 o; o.x = f2b(v.x); o.y = f2b(v.y); o.z = f2b(v.z); o.w = f2b(v.w);
            *(ushort4*)(ygb + rr * DI_ + d0 + q) = o;
        }
        buf ^= 1;
    }
    #undef STAGE
}

// ---------------------------------------------------------------------------
extern "C" void kernel_launch(void* const* d_in, const int* in_sizes, int n_in,
                              void* d_out, int out_size, void* d_ws, size_t ws_size,
                              hipStream_t stream)
{
    const float* x      = (const float*)d_in[0];
    const float* in_w   = (const float*)d_in[1];
    const float* in_b   = (const float*)d_in[2];
    const float* conv_w = (const float*)d_in[3];
    const float* conv_b = (const float*)d_in[4];
    const float* A      = (const float*)d_in[5];
    const float* Dp     = (const float*)d_in[6];
    const float* B_w    = (const float*)d_in[7];
    const float* B_b    = (const float*)d_in[8];
    const float* C_w    = (const float*)d_in[9];
    const float* C_b    = (const float*)d_in[10];
    const float* dt_w   = (const float*)d_in[11];
    const float* dt_b   = (const float*)d_in[12];
    const float* out_w  = (const float*)d_in[13];
    const float* out_b  = (const float*)d_in[14];
    float* out = (float*)d_out;

    // ---- workspace layout (aliased; peak 84.25 MB) ----
    float* xp  = (float*)d_ws;                 // [M][2*DI] fp32, 32MB
    float* xc  = xp  + (size_t)M_ * 2 * DI_;   // [M][DI]   fp32, 16MB
    float* dtb = xc  + (size_t)M_ * DI_;       // [M][DI]   fp32, 16MB
    float* Bm  = dtb + (size_t)M_ * DI_;       // [M][16]
    float* Cm  = Bm  + (size_t)M_ * DS_;       // [M][16]
    unsigned short* w1  = (unsigned short*)(Cm + (size_t)M_ * DS_); // 4M bf16 (8MB): inwt/dtwt/outwt (sequential reuse)
    unsigned short* xb  = w1  + (size_t)4 * 1024 * 1024;            // 2M bf16 (4MB)
    unsigned short* xcb = xb  + (size_t)2 * 1024 * 1024;            // 4M bf16 (8MB)
    unsigned short* ygb = xcb;                                       // alias (xcb dead after dt GEMM)

    // 1) bf16 shadows of x and in_w^T
    cast_bf16<<<(M_ * DM_ / 4 + 255) / 256, 256, 0, stream>>>(x, xb, M_ * DM_);
    transpose_cast<<<dim3(2 * DI_ / 32, DM_ / 32), 256, 0, stream>>>(in_w, w1, DM_, 2 * DI_);

    // 2) xp = x @ in_w + in_b   (M=2048, N=4096, K=1024)
    gemm_mfma<<<dim3(2 * DI_ / 128, M_ / 128), 256, 0, stream>>>(
        xb, w1, in_b, xp, M_, 2 * DI_, DM_, 0);

    // 3) depthwise conv + silu (fp32 + bf16 outputs)
    conv_silu<<<(BN_ * L_ * DI_) / 256, 256, 0, stream>>>(xp, conv_w, conv_b, xc, xcb);

    // 4) Bm, Cm projections
    bc_proj<<<M_, 256, 0, stream>>>(xc, B_w, B_b, C_w, C_b, Bm, Cm);

    // 5) dt = softplus(x_conv @ dt_w + dt_b)   (M=2048, N=2048, K=2048)
    transpose_cast<<<dim3(DI_ / 32, DI_ / 32), 256, 0, stream>>>(dt_w, w1, DI_, DI_);
    gemm_mfma<<<dim3(DI_ / 128, M_ / 128), 256, 0, stream>>>(
        xcb, w1, dt_b, dtb, M_, DI_, DI_, 1);

    // 6) out_w^T (w1 free again after dt GEMM)
    transpose_cast<<<dim3(DM_ / 32, DI_ / 32), 256, 0, stream>>>(out_w, w1, DI_, DM_);

    // 7) scan + skip + gate -> ygb (bf16; aliases xcb, dead by now)
    scan_fused<<<dim3(DI_ / CH_, BN_), 256, 0, stream>>>(
        dtb, xc, xp, Bm, Cm, A, Dp, ygb);

    // 8) out = yg @ out_w + out_b   (M=2048, N=1024, K=2048)
    gemm_mfma<<<dim3(DM_ / 128, M_ / 128), 256, 0, stream>>>(
        ygb, w1, out_b, out, M_, DM_, DI_, 0);
}

// Round 4
// 314.043 us; speedup vs baseline: 4.1631x; 1.5135x over previous
//
#include <hip/hip_runtime.h>
#include <hip/hip_bf16.h>
#include <math.h>

// Problem constants: BN=2, L=1024, DM=1024, D_STATE=16, D_CONV=4, EXPAND=2,
// D_INNER=2048. M = BN*L = 2048.
#define BN_   2
#define L_    1024
#define DM_   1024
#define DS_   16
#define DI_   2048
#define M_    (BN_ * L_)

typedef __attribute__((ext_vector_type(8))) short short8;
typedef __attribute__((ext_vector_type(4))) float f32x4;

__device__ __forceinline__ unsigned short f2b(float f) {
    union { float f; unsigned u; } x; x.f = f;
    unsigned r = x.u + 0x7fffu + ((x.u >> 16) & 1u);   // RNE
    return (unsigned short)(r >> 16);
}

__device__ __forceinline__ void gload_lds16(const unsigned short* g, unsigned short* l) {
    __builtin_amdgcn_global_load_lds(
        (const __attribute__((address_space(1))) void*)g,
        (__attribute__((address_space(3))) void*)l, 16, 0, 0);
}

// ---------------------------------------------------------------------------
// elementwise fp32 -> bf16 cast (n multiple of 4)
// ---------------------------------------------------------------------------
__global__ __launch_bounds__(256) void cast_bf16(
    const float* __restrict__ in, unsigned short* __restrict__ out, int n)
{
    const int i = (blockIdx.x * 256 + threadIdx.x) * 4;
    if (i >= n) return;
    float4 v = *(const float4*)(in + i);
    ushort4 o; o.x = f2b(v.x); o.y = f2b(v.y); o.z = f2b(v.z); o.w = f2b(v.w);
    *(ushort4*)(out + i) = o;
}

// ---------------------------------------------------------------------------
// transpose + cast: in fp32 [R][C] -> out bf16 [C][R].  R,C multiples of 32.
// ---------------------------------------------------------------------------
__global__ __launch_bounds__(256) void transpose_cast(
    const float* __restrict__ in, unsigned short* __restrict__ out, int R, int C)
{
    __shared__ float t[32][33];
    const int bx = blockIdx.x * 32;   // C dir
    const int by = blockIdx.y * 32;   // R dir
    const int tx = threadIdx.x & 31;
    const int ty = (threadIdx.x >> 5) * 4;
    #pragma unroll
    for (int j = 0; j < 4; ++j)
        t[ty + j][tx] = in[(size_t)(by + ty + j) * C + bx + tx];
    __syncthreads();
    #pragma unroll
    for (int j = 0; j < 4; ++j)
        out[(size_t)(bx + ty + j) * R + by + tx] = f2b(t[tx][ty + j]);
}

// ---------------------------------------------------------------------------
// bf16 MFMA GEMM (m97 structure): C[M][N] = A[M][K] @ Bt[N][K]^T + bias.
// 128x128 tile, BK=64, 4 waves (2x2), each wave 64x64 = 4x4 frags of 16x16x32.
// act==1 -> softplus. fp32 accumulate, fp32 output.
// ---------------------------------------------------------------------------
__global__ __launch_bounds__(256) void gemm_mfma(
    const unsigned short* __restrict__ A,   // [M][K] bf16
    const unsigned short* __restrict__ Bt,  // [N][K] bf16
    const float* __restrict__ bias,
    float* __restrict__ C,
    int M, int N, int K, int act)
{
    __shared__ unsigned short Asl[128 * 64];
    __shared__ unsigned short Bsl[128 * 64];

    const int tid  = threadIdx.x;
    const int wave = tid >> 6;
    const int lane = tid & 63;
    const int row0 = blockIdx.y * 128;
    const int col0 = blockIdx.x * 128;
    const int wr   = (wave >> 1) * 64;
    const int wc   = (wave & 1) * 64;

    const int srow = lane >> 3;
    const int scol = (lane & 7) * 8;

    f32x4 acc[4][4];
    #pragma unroll
    for (int m = 0; m < 4; ++m)
        #pragma unroll
        for (int n = 0; n < 4; ++n)
            acc[m][n] = (f32x4){0.f, 0.f, 0.f, 0.f};

    for (int kt = 0; kt < K; kt += 64) {
        #pragma unroll
        for (int i = 0; i < 4; ++i) {
            const int chunk = wave * 4 + i;
            gload_lds16(A  + (size_t)(row0 + chunk * 8 + srow) * K + kt + scol,
                        &Asl[chunk * 512]);
            gload_lds16(Bt + (size_t)(col0 + chunk * 8 + srow) * K + kt + scol,
                        &Bsl[chunk * 512]);
        }
        __syncthreads();

        short8 af[4][2], bf[4][2];
        #pragma unroll
        for (int m = 0; m < 4; ++m)
            #pragma unroll
            for (int kk = 0; kk < 2; ++kk)
                af[m][kk] = *(const short8*)
                    &Asl[(wr + m * 16 + (lane & 15)) * 64 + kk * 32 + (lane >> 4) * 8];
        #pragma unroll
        for (int n = 0; n < 4; ++n)
            #pragma unroll
            for (int kk = 0; kk < 2; ++kk)
                bf[n][kk] = *(const short8*)
                    &Bsl[(wc + n * 16 + (lane & 15)) * 64 + kk * 32 + (lane >> 4) * 8];

        #pragma unroll
        for (int m = 0; m < 4; ++m)
            #pragma unroll
            for (int n = 0; n < 4; ++n) {
                acc[m][n] = __builtin_amdgcn_mfma_f32_16x16x32_bf16(
                    af[m][0], bf[n][0], acc[m][n], 0, 0, 0);
                acc[m][n] = __builtin_amdgcn_mfma_f32_16x16x32_bf16(
                    af[m][1], bf[n][1], acc[m][n], 0, 0, 0);
            }
        __syncthreads();
    }

    const int crow = (lane >> 4) * 4;
    const int ccol = lane & 15;
    #pragma unroll
    for (int m = 0; m < 4; ++m)
        #pragma unroll
        for (int n = 0; n < 4; ++n) {
            const int c = col0 + wc + n * 16 + ccol;
            const float bv = bias[c];
            #pragma unroll
            for (int j = 0; j < 4; ++j) {
                const int r = row0 + wr + m * 16 + crow + j;
                float v = acc[m][n][j] + bv;
                if (act == 1) v = (v > 20.0f) ? v : log1pf(__expf(v));
                C[(size_t)r * N + c] = v;
            }
        }
}

// ---------------------------------------------------------------------------
// Depthwise conv (window 4, SAME: taps t-1..t+2) + bias + SiLU.
// ---------------------------------------------------------------------------
__global__ __launch_bounds__(256) void conv_silu(
    const float* __restrict__ xp, const float* __restrict__ cw,
    const float* __restrict__ cb, float* __restrict__ xc,
    unsigned short* __restrict__ xcb)
{
    const int idx = blockIdx.x * 256 + threadIdx.x;
    if (idx >= BN_ * L_ * DI_) return;
    const int d = idx & (DI_ - 1);
    const int t = (idx / DI_) & (L_ - 1);
    const int b = idx / (DI_ * L_);

    float acc = cb[d];
    #pragma unroll
    for (int w = 0; w < 4; ++w) {
        const int tt = t + w - 1;
        if (tt >= 0 && tt < L_)
            acc = fmaf(xp[((size_t)(b * L_ + tt)) * (2 * DI_) + d], cw[w * DI_ + d], acc);
    }
    const float s = acc / (1.0f + __expf(-acc));
    xc[idx]  = s;
    xcb[idx] = f2b(s);
}

// ---------------------------------------------------------------------------
// B / C projections (N=16 each), fp32.
// ---------------------------------------------------------------------------
__global__ __launch_bounds__(256) void bc_proj(
    const float* __restrict__ xc,
    const float* __restrict__ Bw, const float* __restrict__ Bb,
    const float* __restrict__ Cw, const float* __restrict__ Cb,
    float* __restrict__ Bm, float* __restrict__ Cm)
{
    const int r = blockIdx.x;
    const int tid = threadIdx.x;

    float accB[DS_] = {};
    float accC[DS_] = {};
    for (int k = tid; k < DI_; k += 256) {
        const float xv = xc[(size_t)r * DI_ + k];
        #pragma unroll
        for (int s = 0; s < DS_; ++s) {
            accB[s] = fmaf(xv, Bw[k * DS_ + s], accB[s]);
            accC[s] = fmaf(xv, Cw[k * DS_ + s], accC[s]);
        }
    }
    #pragma unroll
    for (int s = 0; s < DS_; ++s) {
        #pragma unroll
        for (int off = 32; off > 0; off >>= 1) {
            accB[s] += __shfl_down(accB[s], off);
            accC[s] += __shfl_down(accC[s], off);
        }
    }
    __shared__ float redB[4][DS_], redC[4][DS_];
    const int wave = tid >> 6, lane = tid & 63;
    if (lane == 0) {
        #pragma unroll
        for (int s = 0; s < DS_; ++s) { redB[wave][s] = accB[s]; redC[wave][s] = accC[s]; }
    }
    __syncthreads();
    if (tid < DS_) {
        Bm[r * DS_ + tid] = redB[0][tid] + redB[1][tid] + redB[2][tid] + redB[3][tid] + Bb[tid];
        Cm[r * DS_ + tid] = redC[0][tid] + redC[1][tid] + redC[2][tid] + redC[3][tid] + Cb[tid];
    }
}

// ---------------------------------------------------------------------------
// Chunked selective scan over L (linear recurrence -> 2-level scan).
//   pass1: per chunk of TL_ steps, from h=0: local final state Hc and
//          elementwise dA-product Pc.
//   combine: tiny sequential pass over NCH_ chunks; in-place turns Hc into
//          the incoming state Hin per chunk.
//   pass2: per chunk, scan from Hin, full y + skip + silu(gate), bf16 out.
// Block = 16 channels x 16 states; grid (DI/16, BN, NCH).
// ---------------------------------------------------------------------------
#define CH_ 16
#define TL_ 64
#define NCH_ (L_ / TL_)   // 16

__global__ __launch_bounds__(256) void scan_part1(
    const float* __restrict__ dt, const float* __restrict__ xc,
    const float* __restrict__ Bm, const float* __restrict__ A,
    float* __restrict__ Pc, float* __restrict__ Hc)
{
    const int tid = threadIdx.x;
    const int s = tid & 15, c = tid >> 4;
    const int d0 = blockIdx.x * CH_;
    const int b  = blockIdx.y;
    const int j  = blockIdx.z;
    const int t0 = j * TL_;
    const int d  = d0 + c;

    __shared__ float s_dt[TL_][CH_];
    __shared__ float s_xc[TL_][CH_];
    __shared__ float s_Bm[TL_][DS_];

    const int rt = tid >> 2, q = (tid & 3) * 4;
    {
        const size_t rr = (size_t)(b * L_ + t0 + rt);
        *(float4*)&s_dt[rt][q] = *(const float4*)(dt + rr * DI_ + d0 + q);
        *(float4*)&s_xc[rt][q] = *(const float4*)(xc + rr * DI_ + d0 + q);
        *(float4*)&s_Bm[rt][q] = *(const float4*)(Bm + rr * DS_ + q);
    }
    const float a_s = A[(size_t)d * DS_ + s];
    __syncthreads();

    float h = 0.f, P = 1.f;
    #pragma unroll 8
    for (int t = 0; t < TL_; ++t) {
        const float dtv = s_dt[t][c];
        const float xcv = s_xc[t][c];
        const float bm  = s_Bm[t][s];
        const float dA  = __expf(dtv * a_s);
        P *= dA;
        h = fmaf(dA, h, dtv * xcv * bm);
    }
    const size_t o = (((size_t)b * NCH_ + j) * DI_ + d0) * DS_ + tid;  // tid == c*16+s
    Pc[o] = P;
    Hc[o] = h;
}

__global__ __launch_bounds__(256) void scan_combine(
    const float* __restrict__ Pc, float* __restrict__ Hc)
{
    const size_t idx = (size_t)blockIdx.x * 256 + threadIdx.x;  // over BN*DI*DS
    const size_t b  = idx / (DI_ * DS_);
    const size_t ds = idx % (DI_ * DS_);
    float h = 0.f;
    #pragma unroll
    for (int j = 0; j < NCH_; ++j) {
        const size_t o = (b * NCH_ + j) * ((size_t)DI_ * DS_) + ds;
        const float P  = Pc[o];
        const float hl = Hc[o];
        Hc[o] = h;                 // incoming state for chunk j
        h = fmaf(P, h, hl);
    }
}

__global__ __launch_bounds__(256) void scan_part2(
    const float* __restrict__ dt, const float* __restrict__ xc,
    const float* __restrict__ xp,                    // gate = xp[:, DI_:2*DI_]
    const float* __restrict__ Bm, const float* __restrict__ Cm,
    const float* __restrict__ A, const float* __restrict__ Dp,
    const float* __restrict__ Hin, unsigned short* __restrict__ ygb)
{
    const int tid = threadIdx.x;
    const int s = tid & 15, c = tid >> 4;
    const int d0 = blockIdx.x * CH_;
    const int b  = blockIdx.y;
    const int j  = blockIdx.z;
    const int t0 = j * TL_;
    const int d  = d0 + c;

    __shared__ float s_dt[TL_][CH_];
    __shared__ float s_xc[TL_][CH_];
    __shared__ float s_gv[TL_][CH_];
    __shared__ float s_Bm[TL_][DS_];
    __shared__ float s_Cm[TL_][DS_];
    __shared__ float s_y [TL_][CH_];

    const int rt = tid >> 2, q = (tid & 3) * 4;
    {
        const size_t rr = (size_t)(b * L_ + t0 + rt);
        *(float4*)&s_dt[rt][q] = *(const float4*)(dt + rr * DI_ + d0 + q);
        *(float4*)&s_xc[rt][q] = *(const float4*)(xc + rr * DI_ + d0 + q);
        *(float4*)&s_gv[rt][q] = *(const float4*)(xp + rr * 2 * DI_ + DI_ + d0 + q);
        *(float4*)&s_Bm[rt][q] = *(const float4*)(Bm + rr * DS_ + q);
        *(float4*)&s_Cm[rt][q] = *(const float4*)(Cm + rr * DS_ + q);
    }
    const float a_s = A[(size_t)d * DS_ + s];
    const float dp  = Dp[d];
    float h = Hin[(((size_t)b * NCH_ + j) * DI_ + d0) * DS_ + tid];
    __syncthreads();

    #pragma unroll 4
    for (int t = 0; t < TL_; ++t) {
        const float dtv = s_dt[t][c];
        const float xcv = s_xc[t][c];
        const float bm  = s_Bm[t][s];
        const float cm  = s_Cm[t][s];
        const float dA  = __expf(dtv * a_s);
        h = fmaf(dA, h, dtv * xcv * bm);
        float y = h * cm;
        y += __shfl_xor(y, 8);
        y += __shfl_xor(y, 4);
        y += __shfl_xor(y, 2);
        y += __shfl_xor(y, 1);
        if (s == 0) {
            const float gv = s_gv[t][c];
            s_y[t][c] = fmaf(xcv, dp, y) * (gv / (1.0f + __expf(-gv)));
        }
    }

    __syncthreads();
    {
        const size_t rr = (size_t)(b * L_ + t0 + rt);
        float4 v = *(float4*)&s_y[rt][q];
        ushort4 o; o.x = f2b(v.x); o.y = f2b(v.y); o.z = f2b(v.z); o.w = f2b(v.w);
        *(ushort4*)(ygb + rr * DI_ + d0 + q) = o;
    }
}

// ---------------------------------------------------------------------------
extern "C" void kernel_launch(void* const* d_in, const int* in_sizes, int n_in,
                              void* d_out, int out_size, void* d_ws, size_t ws_size,
                              hipStream_t stream)
{
    const float* x      = (const float*)d_in[0];
    const float* in_w   = (const float*)d_in[1];
    const float* in_b   = (const float*)d_in[2];
    const float* conv_w = (const float*)d_in[3];
    const float* conv_b = (const float*)d_in[4];
    const float* A      = (const float*)d_in[5];
    const float* Dp     = (const float*)d_in[6];
    const float* B_w    = (const float*)d_in[7];
    const float* B_b    = (const float*)d_in[8];
    const float* C_w    = (const float*)d_in[9];
    const float* C_b    = (const float*)d_in[10];
    const float* dt_w   = (const float*)d_in[11];
    const float* dt_b   = (const float*)d_in[12];
    const float* out_w  = (const float*)d_in[13];
    const float* out_b  = (const float*)d_in[14];
    float* out = (float*)d_out;

    // ---- workspace layout (aliased; peak 88.25 MB) ----
    float* xp  = (float*)d_ws;                 // [M][2*DI] fp32, 32MB
    float* xc  = xp  + (size_t)M_ * 2 * DI_;   // [M][DI]   fp32, 16MB
    float* dtb = xc  + (size_t)M_ * DI_;       // [M][DI]   fp32, 16MB
    float* Bm  = dtb + (size_t)M_ * DI_;       // [M][16]
    float* Cm  = Bm  + (size_t)M_ * DS_;       // [M][16]
    unsigned short* w1  = (unsigned short*)(Cm + (size_t)M_ * DS_); // 4M bf16 (8MB)
    unsigned short* xb  = w1  + (size_t)4 * 1024 * 1024;            // 2M bf16 (4MB)
    unsigned short* xcb = xb  + (size_t)2 * 1024 * 1024;            // 4M bf16 (8MB)
    unsigned short* ygb = xcb;                         // alias (xcb dead after dt GEMM)
    float* Pc = (float*)xb;                            // alias xb (dead after step 2), 4MB
    float* Hc = (float*)(xcb + (size_t)4 * 1024 * 1024); // +4MB tail (Hc -> Hin in-place)

    // 1) bf16 shadows of x and in_w^T
    cast_bf16<<<(M_ * DM_ / 4 + 255) / 256, 256, 0, stream>>>(x, xb, M_ * DM_);
    transpose_cast<<<dim3(2 * DI_ / 32, DM_ / 32), 256, 0, stream>>>(in_w, w1, DM_, 2 * DI_);

    // 2) xp = x @ in_w + in_b   (M=2048, N=4096, K=1024)
    gemm_mfma<<<dim3(2 * DI_ / 128, M_ / 128), 256, 0, stream>>>(
        xb, w1, in_b, xp, M_, 2 * DI_, DM_, 0);

    // 3) depthwise conv + silu (fp32 + bf16 outputs)
    conv_silu<<<(BN_ * L_ * DI_) / 256, 256, 0, stream>>>(xp, conv_w, conv_b, xc, xcb);

    // 4) Bm, Cm projections
    bc_proj<<<M_, 256, 0, stream>>>(xc, B_w, B_b, C_w, C_b, Bm, Cm);

    // 5) dt = softplus(x_conv @ dt_w + dt_b)   (M=2048, N=2048, K=2048)
    transpose_cast<<<dim3(DI_ / 32, DI_ / 32), 256, 0, stream>>>(dt_w, w1, DI_, DI_);
    gemm_mfma<<<dim3(DI_ / 128, M_ / 128), 256, 0, stream>>>(
        xcb, w1, dt_b, dtb, M_, DI_, DI_, 1);

    // 6) out_w^T (w1 free again after dt GEMM)
    transpose_cast<<<dim3(DM_ / 32, DI_ / 32), 256, 0, stream>>>(out_w, w1, DI_, DM_);

    // 7) chunked scan: part1 -> combine -> part2 (writes bf16 ygb)
    scan_part1<<<dim3(DI_ / CH_, BN_, NCH_), 256, 0, stream>>>(
        dtb, xc, Bm, A, Pc, Hc);
    scan_combine<<<(BN_ * DI_ * DS_) / 256, 256, 0, stream>>>(Pc, Hc);
    scan_part2<<<dim3(DI_ / CH_, BN_, NCH_), 256, 0, stream>>>(
        dtb, xc, xp, Bm, Cm, A, Dp, Hc, ygb);

    // 8) out = yg @ out_w + out_b   (M=2048, N=1024, K=2048)
    gemm_mfma<<<dim3(DM_ / 128, M_ / 128), 256, 0, stream>>>(
        ygb, w1, out_b, out, M_, DM_, DI_, 0);
}

// Round 5
// 264.204 us; speedup vs baseline: 4.9485x; 1.1886x over previous
//
#include <hip/hip_runtime.h>
#include <hip/hip_bf16.h>
#include <math.h>

// Problem constants: BN=2, L=1024, DM=1024, D_STATE=16, D_CONV=4, EXPAND=2,
// D_INNER=2048. M = BN*L = 2048.
#define BN_   2
#define L_    1024
#define DM_   1024
#define DS_   16
#define DI_   2048
#define M_    (BN_ * L_)

typedef __attribute__((ext_vector_type(8))) short short8;
typedef __attribute__((ext_vector_type(4))) float f32x4;

__device__ __forceinline__ unsigned short f2b(float f) {
    union { float f; unsigned u; } x; x.f = f;
    unsigned r = x.u + 0x7fffu + ((x.u >> 16) & 1u);   // RNE
    return (unsigned short)(r >> 16);
}

__device__ __forceinline__ void gload_lds16(const unsigned short* g, unsigned short* l) {
    __builtin_amdgcn_global_load_lds(
        (const __attribute__((address_space(1))) void*)g,
        (__attribute__((address_space(3))) void*)l, 16, 0, 0);
}

// ---------------------------------------------------------------------------
// elementwise fp32 -> bf16 cast (n multiple of 4)
// ---------------------------------------------------------------------------
__global__ __launch_bounds__(256) void cast_bf16(
    const float* __restrict__ in, unsigned short* __restrict__ out, int n)
{
    const int i = (blockIdx.x * 256 + threadIdx.x) * 4;
    if (i >= n) return;
    float4 v = *(const float4*)(in + i);
    ushort4 o; o.x = f2b(v.x); o.y = f2b(v.y); o.z = f2b(v.z); o.w = f2b(v.w);
    *(ushort4*)(out + i) = o;
}

// ---------------------------------------------------------------------------
// transpose + cast: in fp32 [R][C] -> out bf16 [C][R].  R,C multiples of 32.
// ---------------------------------------------------------------------------
__global__ __launch_bounds__(256) void transpose_cast(
    const float* __restrict__ in, unsigned short* __restrict__ out, int R, int C)
{
    __shared__ float t[32][33];
    const int bx = blockIdx.x * 32;   // C dir
    const int by = blockIdx.y * 32;   // R dir
    const int tx = threadIdx.x & 31;
    const int ty = (threadIdx.x >> 5) * 4;
    #pragma unroll
    for (int j = 0; j < 4; ++j)
        t[ty + j][tx] = in[(size_t)(by + ty + j) * C + bx + tx];
    __syncthreads();
    #pragma unroll
    for (int j = 0; j < 4; ++j)
        out[(size_t)(bx + ty + j) * R + by + tx] = f2b(t[tx][ty + j]);
}

// ---------------------------------------------------------------------------
// bf16 MFMA GEMM (m97 structure): C[M][N] = A[M][K] @ Bt[N][K]^T + bias.
// 128x128 tile, BK=64, 4 waves (2x2), 16x16x32 frags. fp32 out.
// Epilogue splits output columns: c < NS -> C0[r][c], else C1[r][c-NS].
// For unsplit callers pass NS=N, C1 arbitrary.
// act==1 -> softplus.
// ---------------------------------------------------------------------------
__global__ __launch_bounds__(256) void gemm_mfma(
    const unsigned short* __restrict__ A,   // [M][K] bf16
    const unsigned short* __restrict__ Bt,  // [N][K] bf16
    const float* __restrict__ bias,
    float* __restrict__ C0, float* __restrict__ C1,
    int M, int N, int K, int NS, int act)
{
    __shared__ unsigned short Asl[128 * 64];
    __shared__ unsigned short Bsl[128 * 64];

    const int tid  = threadIdx.x;
    const int wave = tid >> 6;
    const int lane = tid & 63;
    const int row0 = blockIdx.y * 128;
    const int col0 = blockIdx.x * 128;
    const int wr   = (wave >> 1) * 64;
    const int wc   = (wave & 1) * 64;

    const int srow = lane >> 3;
    const int scol = (lane & 7) * 8;

    f32x4 acc[4][4];
    #pragma unroll
    for (int m = 0; m < 4; ++m)
        #pragma unroll
        for (int n = 0; n < 4; ++n)
            acc[m][n] = (f32x4){0.f, 0.f, 0.f, 0.f};

    for (int kt = 0; kt < K; kt += 64) {
        #pragma unroll
        for (int i = 0; i < 4; ++i) {
            const int chunk = wave * 4 + i;
            gload_lds16(A  + (size_t)(row0 + chunk * 8 + srow) * K + kt + scol,
                        &Asl[chunk * 512]);
            gload_lds16(Bt + (size_t)(col0 + chunk * 8 + srow) * K + kt + scol,
                        &Bsl[chunk * 512]);
        }
        __syncthreads();

        short8 af[4][2], bf[4][2];
        #pragma unroll
        for (int m = 0; m < 4; ++m)
            #pragma unroll
            for (int kk = 0; kk < 2; ++kk)
                af[m][kk] = *(const short8*)
                    &Asl[(wr + m * 16 + (lane & 15)) * 64 + kk * 32 + (lane >> 4) * 8];
        #pragma unroll
        for (int n = 0; n < 4; ++n)
            #pragma unroll
            for (int kk = 0; kk < 2; ++kk)
                bf[n][kk] = *(const short8*)
                    &Bsl[(wc + n * 16 + (lane & 15)) * 64 + kk * 32 + (lane >> 4) * 8];

        #pragma unroll
        for (int m = 0; m < 4; ++m)
            #pragma unroll
            for (int n = 0; n < 4; ++n) {
                acc[m][n] = __builtin_amdgcn_mfma_f32_16x16x32_bf16(
                    af[m][0], bf[n][0], acc[m][n], 0, 0, 0);
                acc[m][n] = __builtin_amdgcn_mfma_f32_16x16x32_bf16(
                    af[m][1], bf[n][1], acc[m][n], 0, 0, 0);
            }
        __syncthreads();
    }

    const int crow = (lane >> 4) * 4;
    const int ccol = lane & 15;
    #pragma unroll
    for (int m = 0; m < 4; ++m)
        #pragma unroll
        for (int n = 0; n < 4; ++n) {
            const int c = col0 + wc + n * 16 + ccol;
            const float bv = bias[c];
            float* dst = (c < NS) ? (C0 + c) : (C1 + (c - NS));
            #pragma unroll
            for (int j = 0; j < 4; ++j) {
                const int r = row0 + wr + m * 16 + crow + j;
                float v = acc[m][n][j] + bv;
                if (act == 1) v = (v > 20.0f) ? v : log1pf(__expf(v));
                dst[(size_t)r * NS] = v;
            }
        }
}

// ---------------------------------------------------------------------------
// Depthwise conv (window 4, SAME: taps t-1..t+2) + bias + SiLU.
// Reads xz [M][DI]; writes fp32 xc and bf16 xcb.
// ---------------------------------------------------------------------------
__global__ __launch_bounds__(256) void conv_silu(
    const float* __restrict__ xz, const float* __restrict__ cw,
    const float* __restrict__ cb, float* __restrict__ xc,
    unsigned short* __restrict__ xcb)
{
    const int idx = blockIdx.x * 256 + threadIdx.x;
    if (idx >= BN_ * L_ * DI_) return;
    const int d = idx & (DI_ - 1);
    const int t = (idx / DI_) & (L_ - 1);
    const int b = idx / (DI_ * L_);

    float acc = cb[d];
    #pragma unroll
    for (int w = 0; w < 4; ++w) {
        const int tt = t + w - 1;
        if (tt >= 0 && tt < L_)
            acc = fmaf(xz[((size_t)(b * L_ + tt)) * DI_ + d], cw[w * DI_ + d], acc);
    }
    const float s = acc / (1.0f + __expf(-acc));
    xc[idx]  = s;
    xcb[idx] = f2b(s);
}

// ---------------------------------------------------------------------------
// B / C projections (N=16 each), fp32.
// ---------------------------------------------------------------------------
__global__ __launch_bounds__(256) void bc_proj(
    const float* __restrict__ xc,
    const float* __restrict__ Bw, const float* __restrict__ Bb,
    const float* __restrict__ Cw, const float* __restrict__ Cb,
    float* __restrict__ Bm, float* __restrict__ Cm)
{
    const int r = blockIdx.x;
    const int tid = threadIdx.x;

    float accB[DS_] = {};
    float accC[DS_] = {};
    for (int k = tid; k < DI_; k += 256) {
        const float xv = xc[(size_t)r * DI_ + k];
        #pragma unroll
        for (int s = 0; s < DS_; ++s) {
            accB[s] = fmaf(xv, Bw[k * DS_ + s], accB[s]);
            accC[s] = fmaf(xv, Cw[k * DS_ + s], accC[s]);
        }
    }
    #pragma unroll
    for (int s = 0; s < DS_; ++s) {
        #pragma unroll
        for (int off = 32; off > 0; off >>= 1) {
            accB[s] += __shfl_down(accB[s], off);
            accC[s] += __shfl_down(accC[s], off);
        }
    }
    __shared__ float redB[4][DS_], redC[4][DS_];
    const int wave = tid >> 6, lane = tid & 63;
    if (lane == 0) {
        #pragma unroll
        for (int s = 0; s < DS_; ++s) { redB[wave][s] = accB[s]; redC[wave][s] = accC[s]; }
    }
    __syncthreads();
    if (tid < DS_) {
        Bm[r * DS_ + tid] = redB[0][tid] + redB[1][tid] + redB[2][tid] + redB[3][tid] + Bb[tid];
        Cm[r * DS_ + tid] = redC[0][tid] + redC[1][tid] + redC[2][tid] + redC[3][tid] + Cb[tid];
    }
}

// ---------------------------------------------------------------------------
// Chunked selective scan, one CHANNEL per lane, 16 states in registers.
// NCH_ chunks of TL_ steps. Bm/Cm chunk broadcast from LDS; dt/xc/gate
// read coalesced from global with t+1 prefetch. Pc/Hc layout [b][j][s][d]
// so all global accesses are d-coalesced.
// ---------------------------------------------------------------------------
#define NCH_ 32
#define TL_  (L_ / NCH_)   // 32

__global__ __launch_bounds__(256) void scan_part1(
    const float* __restrict__ dt, const float* __restrict__ xc,
    const float* __restrict__ Bm, const float* __restrict__ A,
    float* __restrict__ Pc, float* __restrict__ Hc)
{
    const int tid = threadIdx.x;
    const int d   = blockIdx.x * 256 + tid;
    const int b   = blockIdx.y;
    const int j   = blockIdx.z;
    const int t0  = j * TL_;

    __shared__ float s_Bm[TL_ * DS_];                  // 2 KB, contiguous chunk
    {
        const float* src = Bm + ((size_t)b * L_ + t0) * DS_;
        s_Bm[tid]       = src[tid];
        s_Bm[256 + tid] = src[256 + tid];
    }
    float a[DS_];
    #pragma unroll
    for (int qq = 0; qq < 4; ++qq)
        *(float4*)&a[qq * 4] = *(const float4*)(A + (size_t)d * DS_ + qq * 4);
    __syncthreads();

    const float* dtp = dt + ((size_t)b * L_ + t0) * DI_ + d;
    const float* xcp = xc + ((size_t)b * L_ + t0) * DI_ + d;

    float h[DS_] = {};
    float P[DS_];
    #pragma unroll
    for (int s = 0; s < DS_; ++s) P[s] = 1.0f;

    float dtv = dtp[0], xcv = xcp[0];
    #pragma unroll 4
    for (int t = 0; t < TL_; ++t) {
        float dtv_n = 0.f, xcv_n = 0.f;
        if (t + 1 < TL_) {
            dtv_n = dtp[(size_t)(t + 1) * DI_];
            xcv_n = xcp[(size_t)(t + 1) * DI_];
        }
        const float dx = dtv * xcv;
        #pragma unroll
        for (int qq = 0; qq < 4; ++qq) {
            const float4 bm = *(const float4*)&s_Bm[t * DS_ + qq * 4];
            #pragma unroll
            for (int i = 0; i < 4; ++i) {
                const int s = qq * 4 + i;
                const float bv = (i == 0) ? bm.x : (i == 1) ? bm.y : (i == 2) ? bm.z : bm.w;
                const float dA = __expf(dtv * a[s]);
                P[s] *= dA;
                h[s] = fmaf(dA, h[s], dx * bv);
            }
        }
        dtv = dtv_n; xcv = xcv_n;
    }
    const size_t o0 = (((size_t)b * NCH_ + j) * DS_) * DI_ + d;
    #pragma unroll
    for (int s = 0; s < DS_; ++s) {
        Pc[o0 + (size_t)s * DI_] = P[s];
        Hc[o0 + (size_t)s * DI_] = h[s];
    }
}

__global__ __launch_bounds__(256) void scan_combine(
    const float* __restrict__ Pc, float* __restrict__ Hc)
{
    const size_t idx = (size_t)blockIdx.x * 256 + threadIdx.x;   // over BN*DS*DI
    const size_t b   = idx / (DS_ * DI_);
    const size_t rem = idx % (DS_ * DI_);
    const size_t base   = b * ((size_t)NCH_ * DS_ * DI_) + rem;
    const size_t stride = (size_t)DS_ * DI_;
    float h = 0.f;
    #pragma unroll
    for (int j = 0; j < NCH_; ++j) {
        const size_t o = base + (size_t)j * stride;
        const float P  = Pc[o];
        const float hl = Hc[o];
        Hc[o] = h;                 // incoming state for chunk j
        h = fmaf(P, h, hl);
    }
}

__global__ __launch_bounds__(256) void scan_part2(
    const float* __restrict__ dt, const float* __restrict__ xc,
    const float* __restrict__ gate,
    const float* __restrict__ Bm, const float* __restrict__ Cm,
    const float* __restrict__ A, const float* __restrict__ Dp,
    const float* __restrict__ Hin, unsigned short* __restrict__ ygb)
{
    const int tid = threadIdx.x;
    const int d   = blockIdx.x * 256 + tid;
    const int b   = blockIdx.y;
    const int j   = blockIdx.z;
    const int t0  = j * TL_;

    __shared__ float s_Bm[TL_ * DS_];
    __shared__ float s_Cm[TL_ * DS_];
    {
        const float* bsrc = Bm + ((size_t)b * L_ + t0) * DS_;
        const float* csrc = Cm + ((size_t)b * L_ + t0) * DS_;
        s_Bm[tid]       = bsrc[tid];
        s_Bm[256 + tid] = bsrc[256 + tid];
        s_Cm[tid]       = csrc[tid];
        s_Cm[256 + tid] = csrc[256 + tid];
    }
    float a[DS_];
    #pragma unroll
    for (int qq = 0; qq < 4; ++qq)
        *(float4*)&a[qq * 4] = *(const float4*)(A + (size_t)d * DS_ + qq * 4);
    const float dp = Dp[d];

    float h[DS_];
    {
        const size_t o0 = (((size_t)b * NCH_ + j) * DS_) * DI_ + d;
        #pragma unroll
        for (int s = 0; s < DS_; ++s) h[s] = Hin[o0 + (size_t)s * DI_];
    }
    __syncthreads();

    const size_t rbase = ((size_t)b * L_ + t0) * DI_ + d;
    const float* dtp = dt   + rbase;
    const float* xcp = xc   + rbase;
    const float* gvp = gate + rbase;
    unsigned short* yp = ygb + rbase;

    float dtv = dtp[0], xcv = xcp[0], gv = gvp[0];
    #pragma unroll 4
    for (int t = 0; t < TL_; ++t) {
        float dtv_n = 0.f, xcv_n = 0.f, gv_n = 0.f;
        if (t + 1 < TL_) {
            dtv_n = dtp[(size_t)(t + 1) * DI_];
            xcv_n = xcp[(size_t)(t + 1) * DI_];
            gv_n  = gvp[(size_t)(t + 1) * DI_];
        }
        const float dx = dtv * xcv;
        float y0 = 0.f, y1 = 0.f, y2 = 0.f, y3 = 0.f;
        #pragma unroll
        for (int qq = 0; qq < 4; ++qq) {
            const float4 bm = *(const float4*)&s_Bm[t * DS_ + qq * 4];
            const float4 cm = *(const float4*)&s_Cm[t * DS_ + qq * 4];
            #pragma unroll
            for (int i = 0; i < 4; ++i) {
                const int s = qq * 4 + i;
                const float bv = (i == 0) ? bm.x : (i == 1) ? bm.y : (i == 2) ? bm.z : bm.w;
                const float cv = (i == 0) ? cm.x : (i == 1) ? cm.y : (i == 2) ? cm.z : cm.w;
                const float dA = __expf(dtv * a[s]);
                h[s] = fmaf(dA, h[s], dx * bv);
                if (i == 0) y0 = fmaf(h[s], cv, y0);
                else if (i == 1) y1 = fmaf(h[s], cv, y1);
                else if (i == 2) y2 = fmaf(h[s], cv, y2);
                else y3 = fmaf(h[s], cv, y3);
            }
        }
        float y = (y0 + y1) + (y2 + y3);
        y = fmaf(xcv, dp, y);
        const float r = y * (gv / (1.0f + __expf(-gv)));
        yp[(size_t)t * DI_] = f2b(r);
        dtv = dtv_n; xcv = xcv_n; gv = gv_n;
    }
}

// ---------------------------------------------------------------------------
extern "C" void kernel_launch(void* const* d_in, const int* in_sizes, int n_in,
                              void* d_out, int out_size, void* d_ws, size_t ws_size,
                              hipStream_t stream)
{
    const float* x      = (const float*)d_in[0];
    const float* in_w   = (const float*)d_in[1];
    const float* in_b   = (const float*)d_in[2];
    const float* conv_w = (const float*)d_in[3];
    const float* conv_b = (const float*)d_in[4];
    const float* A      = (const float*)d_in[5];
    const float* Dp     = (const float*)d_in[6];
    const float* B_w    = (const float*)d_in[7];
    const float* B_b    = (const float*)d_in[8];
    const float* C_w    = (const float*)d_in[9];
    const float* C_b    = (const float*)d_in[10];
    const float* dt_w   = (const float*)d_in[11];
    const float* dt_b   = (const float*)d_in[12];
    const float* out_w  = (const float*)d_in[13];
    const float* out_b  = (const float*)d_in[14];
    float* out = (float*)d_out;

    // ---- workspace layout (aliased; peak 84.25 MB) ----
    float* xz   = (float*)d_ws;                 // [M][DI] fp32, 16MB (dead after conv)
    float* gate = xz   + (size_t)M_ * DI_;      // [M][DI] fp32, 16MB
    float* xc   = gate + (size_t)M_ * DI_;      // [M][DI] fp32, 16MB
    float* dtb  = xc   + (size_t)M_ * DI_;      // [M][DI] fp32, 16MB
    float* Bm   = dtb  + (size_t)M_ * DI_;      // [M][16]
    float* Cm   = Bm   + (size_t)M_ * DS_;      // [M][16]
    unsigned short* w1  = (unsigned short*)(Cm + (size_t)M_ * DS_); // 4M bf16 (8MB)
    unsigned short* xb  = w1  + (size_t)4 * 1024 * 1024;            // 2M bf16 (4MB)
    unsigned short* xcb = xb  + (size_t)2 * 1024 * 1024;            // 4M bf16 (8MB)
    unsigned short* ygb = xcb;                  // alias (xcb dead after dt GEMM)
    float* Pc = xz;                             // alias xz (dead after conv), 8MB
    float* Hc = xz + (size_t)BN_ * NCH_ * DS_ * DI_;   // second half of xz, 8MB

    // 1) bf16 shadows of x and in_w^T
    cast_bf16<<<(M_ * DM_ / 4 + 255) / 256, 256, 0, stream>>>(x, xb, M_ * DM_);
    transpose_cast<<<dim3(2 * DI_ / 32, DM_ / 32), 256, 0, stream>>>(in_w, w1, DM_, 2 * DI_);

    // 2) [xz | gate] = x @ in_w + in_b   (M=2048, N=4096, K=1024, split at 2048)
    gemm_mfma<<<dim3(2 * DI_ / 128, M_ / 128), 256, 0, stream>>>(
        xb, w1, in_b, xz, gate, M_, 2 * DI_, DM_, DI_, 0);

    // 3) depthwise conv + silu (fp32 + bf16 outputs)
    conv_silu<<<(BN_ * L_ * DI_) / 256, 256, 0, stream>>>(xz, conv_w, conv_b, xc, xcb);

    // 4) Bm, Cm projections
    bc_proj<<<M_, 256, 0, stream>>>(xc, B_w, B_b, C_w, C_b, Bm, Cm);

    // 5) dt = softplus(x_conv @ dt_w + dt_b)   (M=2048, N=2048, K=2048)
    transpose_cast<<<dim3(DI_ / 32, DI_ / 32), 256, 0, stream>>>(dt_w, w1, DI_, DI_);
    gemm_mfma<<<dim3(DI_ / 128, M_ / 128), 256, 0, stream>>>(
        xcb, w1, dt_b, dtb, dtb, M_, DI_, DI_, DI_, 1);

    // 6) out_w^T (w1 free again after dt GEMM)
    transpose_cast<<<dim3(DM_ / 32, DI_ / 32), 256, 0, stream>>>(out_w, w1, DI_, DM_);

    // 7) chunked scan: part1 -> combine -> part2 (writes bf16 ygb)
    scan_part1<<<dim3(DI_ / 256, BN_, NCH_), 256, 0, stream>>>(
        dtb, xc, Bm, A, Pc, Hc);
    scan_combine<<<(BN_ * DI_ * DS_) / 256, 256, 0, stream>>>(Pc, Hc);
    scan_part2<<<dim3(DI_ / 256, BN_, NCH_), 256, 0, stream>>>(
        dtb, xc, gate, Bm, Cm, A, Dp, Hc, ygb);

    // 8) out = yg @ out_w + out_b   (M=2048, N=1024, K=2048)
    gemm_mfma<<<dim3(DM_ / 128, M_ / 128), 256, 0, stream>>>(
        ygb, w1, out_b, out, out, M_, DM_, DI_, DM_, 0);
}

// Round 6
// 243.661 us; speedup vs baseline: 5.3657x; 1.0843x over previous
//
#include <hip/hip_runtime.h>
#include <hip/hip_bf16.h>
#include <math.h>

// Problem constants: BN=2, L=1024, DM=1024, D_STATE=16, D_CONV=4, EXPAND=2,
// D_INNER=2048. M = BN*L = 2048.
#define BN_   2
#define L_    1024
#define DM_   1024
#define DS_   16
#define DI_   2048
#define M_    (BN_ * L_)

typedef __attribute__((ext_vector_type(8))) short short8;
typedef __attribute__((ext_vector_type(4))) float f32x4;

__device__ __forceinline__ unsigned short f2b(float f) {
    union { float f; unsigned u; } x; x.f = f;
    unsigned r = x.u + 0x7fffu + ((x.u >> 16) & 1u);   // RNE
    return (unsigned short)(r >> 16);
}

__device__ __forceinline__ void gload_lds16(const unsigned short* g, unsigned short* l) {
    __builtin_amdgcn_global_load_lds(
        (const __attribute__((address_space(1))) void*)g,
        (__attribute__((address_space(3))) void*)l, 16, 0, 0);
}

// ---------------------------------------------------------------------------
// elementwise fp32 -> bf16 cast (n multiple of 4)
// ---------------------------------------------------------------------------
__global__ __launch_bounds__(256) void cast_bf16(
    const float* __restrict__ in, unsigned short* __restrict__ out, int n)
{
    const int i = (blockIdx.x * 256 + threadIdx.x) * 4;
    if (i >= n) return;
    float4 v = *(const float4*)(in + i);
    ushort4 o; o.x = f2b(v.x); o.y = f2b(v.y); o.z = f2b(v.z); o.w = f2b(v.w);
    *(ushort4*)(out + i) = o;
}

// ---------------------------------------------------------------------------
// transpose + cast: in fp32 [R][C] -> out bf16 [C][R].  R,C multiples of 32.
// ---------------------------------------------------------------------------
__global__ __launch_bounds__(256) void transpose_cast(
    const float* __restrict__ in, unsigned short* __restrict__ out, int R, int C)
{
    __shared__ float t[32][33];
    const int bx = blockIdx.x * 32;   // C dir
    const int by = blockIdx.y * 32;   // R dir
    const int tx = threadIdx.x & 31;
    const int ty = (threadIdx.x >> 5) * 4;
    #pragma unroll
    for (int j = 0; j < 4; ++j)
        t[ty + j][tx] = in[(size_t)(by + ty + j) * C + bx + tx];
    __syncthreads();
    #pragma unroll
    for (int j = 0; j < 4; ++j)
        out[(size_t)(bx + ty + j) * R + by + tx] = f2b(t[tx][ty + j]);
}

// ---------------------------------------------------------------------------
// bf16 MFMA GEMM, 2-phase double-buffered (T3 minimum recipe) + LDS XOR
// swizzle (T2 adapted, rule #21 both-sides):
//   C[M][N] = A[M][K] @ Bt[N][K]^T + bias
//   128x128 tile, BK=64, 4 waves (2x2), 16x16x32 frags, fp32 out.
//   - global_load_lds dest stays LINEAR; the SOURCE column is pre-swizzled
//     per lane (scol = ((lane&7)^(lane>>3))*8, an involution), so LDS holds
//     row r's column c at element c ^ ((r&7)*8).
//   - ds_read applies the same XOR -> bank-conflict-free (floor 8cy/b128).
//   - next K-tile staged BEFORE current tile's ds_read+MFMA; single
//     __syncthreads per K-step (its vmcnt(0) waits on overlapped loads).
// Epilogue splits output columns: c < NS -> C0[r][c], else C1[r][c-NS].
// act==1 -> softplus.
// ---------------------------------------------------------------------------
__device__ __forceinline__ void stage_tile(
    const unsigned short* __restrict__ A, const unsigned short* __restrict__ Bt,
    unsigned short* As, unsigned short* Bs,
    int row0, int col0, int K, int kt, int wave, int srow, int scol)
{
    #pragma unroll
    for (int i = 0; i < 4; ++i) {
        const int chunk = wave * 4 + i;
        gload_lds16(A  + (size_t)(row0 + chunk * 8 + srow) * K + kt + scol,
                    As + chunk * 512);
        gload_lds16(Bt + (size_t)(col0 + chunk * 8 + srow) * K + kt + scol,
                    Bs + chunk * 512);
    }
}

__global__ __launch_bounds__(256) void gemm_mfma(
    const unsigned short* __restrict__ A,   // [M][K] bf16
    const unsigned short* __restrict__ Bt,  // [N][K] bf16
    const float* __restrict__ bias,
    float* __restrict__ C0, float* __restrict__ C1,
    int M, int N, int K, int NS, int act)
{
    __shared__ unsigned short Asl[2][128 * 64];
    __shared__ unsigned short Bsl[2][128 * 64];

    const int tid  = threadIdx.x;
    const int wave = tid >> 6;
    const int lane = tid & 63;
    const int row0 = blockIdx.y * 128;
    const int col0 = blockIdx.x * 128;
    const int wr   = (wave >> 1) * 64;
    const int wc   = (wave & 1) * 64;

    const int srow = lane >> 3;                          // row within 8-row chunk
    const int scol = ((lane & 7) ^ (lane >> 3)) * 8;     // swizzled source col

    f32x4 acc[4][4];
    #pragma unroll
    for (int m = 0; m < 4; ++m)
        #pragma unroll
        for (int n = 0; n < 4; ++n)
            acc[m][n] = (f32x4){0.f, 0.f, 0.f, 0.f};

    stage_tile(A, Bt, Asl[0], Bsl[0], row0, col0, K, 0, wave, srow, scol);
    __syncthreads();

    const int nk = K >> 6;
    int cur = 0;
    for (int kt = 0; kt < nk; ++kt) {
        if (kt + 1 < nk)
            stage_tile(A, Bt, Asl[cur ^ 1], Bsl[cur ^ 1],
                       row0, col0, K, (kt + 1) << 6, wave, srow, scol);

        short8 af[4][2], bf[4][2];
        const int lrow = lane & 15;
        const int xsw  = (lane & 7) * 8;                 // read-side XOR
        const int cbase = (lane >> 4) * 8;
        #pragma unroll
        for (int m = 0; m < 4; ++m)
            #pragma unroll
            for (int kk = 0; kk < 2; ++kk)
                af[m][kk] = *(const short8*)
                    &Asl[cur][(wr + m * 16 + lrow) * 64 + ((kk * 32 + cbase) ^ xsw)];
        #pragma unroll
        for (int n = 0; n < 4; ++n)
            #pragma unroll
            for (int kk = 0; kk < 2; ++kk)
                bf[n][kk] = *(const short8*)
                    &Bsl[cur][(wc + n * 16 + lrow) * 64 + ((kk * 32 + cbase) ^ xsw)];

        #pragma unroll
        for (int m = 0; m < 4; ++m)
            #pragma unroll
            for (int n = 0; n < 4; ++n) {
                acc[m][n] = __builtin_amdgcn_mfma_f32_16x16x32_bf16(
                    af[m][0], bf[n][0], acc[m][n], 0, 0, 0);
                acc[m][n] = __builtin_amdgcn_mfma_f32_16x16x32_bf16(
                    af[m][1], bf[n][1], acc[m][n], 0, 0, 0);
            }
        __syncthreads();   // drains prefetch vmcnt + protects cur from overwrite
        cur ^= 1;
    }

    // epilogue: C/D layout col=lane&15, row=(lane>>4)*4+j  [m89/m91 verified]
    const int crow = (lane >> 4) * 4;
    const int ccol = lane & 15;
    #pragma unroll
    for (int m = 0; m < 4; ++m)
        #pragma unroll
        for (int n = 0; n < 4; ++n) {
            const int c = col0 + wc + n * 16 + ccol;
            const float bv = bias[c];
            float* dst = (c < NS) ? (C0 + c) : (C1 + (c - NS));
            #pragma unroll
            for (int j = 0; j < 4; ++j) {
                const int r = row0 + wr + m * 16 + crow + j;
                float v = acc[m][n][j] + bv;
                if (act == 1) v = (v > 20.0f) ? v : log1pf(__expf(v));
                dst[(size_t)r * NS] = v;
            }
        }
}

// ---------------------------------------------------------------------------
// Depthwise conv (window 4, SAME: taps t-1..t+2) + bias + SiLU.
// Reads xz [M][DI]; writes fp32 xc and bf16 xcb.
// ---------------------------------------------------------------------------
__global__ __launch_bounds__(256) void conv_silu(
    const float* __restrict__ xz, const float* __restrict__ cw,
    const float* __restrict__ cb, float* __restrict__ xc,
    unsigned short* __restrict__ xcb)
{
    const int idx = blockIdx.x * 256 + threadIdx.x;
    if (idx >= BN_ * L_ * DI_) return;
    const int d = idx & (DI_ - 1);
    const int t = (idx / DI_) & (L_ - 1);
    const int b = idx / (DI_ * L_);

    float acc = cb[d];
    #pragma unroll
    for (int w = 0; w < 4; ++w) {
        const int tt = t + w - 1;
        if (tt >= 0 && tt < L_)
            acc = fmaf(xz[((size_t)(b * L_ + tt)) * DI_ + d], cw[w * DI_ + d], acc);
    }
    const float s = acc / (1.0f + __expf(-acc));
    xc[idx]  = s;
    xcb[idx] = f2b(s);
}

// ---------------------------------------------------------------------------
// B / C projections (N=16 each), fp32.
// ---------------------------------------------------------------------------
__global__ __launch_bounds__(256) void bc_proj(
    const float* __restrict__ xc,
    const float* __restrict__ Bw, const float* __restrict__ Bb,
    const float* __restrict__ Cw, const float* __restrict__ Cb,
    float* __restrict__ Bm, float* __restrict__ Cm)
{
    const int r = blockIdx.x;
    const int tid = threadIdx.x;

    float accB[DS_] = {};
    float accC[DS_] = {};
    for (int k = tid; k < DI_; k += 256) {
        const float xv = xc[(size_t)r * DI_ + k];
        #pragma unroll
        for (int s = 0; s < DS_; ++s) {
            accB[s] = fmaf(xv, Bw[k * DS_ + s], accB[s]);
            accC[s] = fmaf(xv, Cw[k * DS_ + s], accC[s]);
        }
    }
    #pragma unroll
    for (int s = 0; s < DS_; ++s) {
        #pragma unroll
        for (int off = 32; off > 0; off >>= 1) {
            accB[s] += __shfl_down(accB[s], off);
            accC[s] += __shfl_down(accC[s], off);
        }
    }
    __shared__ float redB[4][DS_], redC[4][DS_];
    const int wave = tid >> 6, lane = tid & 63;
    if (lane == 0) {
        #pragma unroll
        for (int s = 0; s < DS_; ++s) { redB[wave][s] = accB[s]; redC[wave][s] = accC[s]; }
    }
    __syncthreads();
    if (tid < DS_) {
        Bm[r * DS_ + tid] = redB[0][tid] + redB[1][tid] + redB[2][tid] + redB[3][tid] + Bb[tid];
        Cm[r * DS_ + tid] = redC[0][tid] + redC[1][tid] + redC[2][tid] + redC[3][tid] + Cb[tid];
    }
}

// ---------------------------------------------------------------------------
// Chunked selective scan, one CHANNEL per lane, 16 states in registers.
// ---------------------------------------------------------------------------
#define NCH_ 32
#define TL_  (L_ / NCH_)   // 32

__global__ __launch_bounds__(256) void scan_part1(
    const float* __restrict__ dt, const float* __restrict__ xc,
    const float* __restrict__ Bm, const float* __restrict__ A,
    float* __restrict__ Pc, float* __restrict__ Hc)
{
    const int tid = threadIdx.x;
    const int d   = blockIdx.x * 256 + tid;
    const int b   = blockIdx.y;
    const int j   = blockIdx.z;
    const int t0  = j * TL_;

    __shared__ float s_Bm[TL_ * DS_];                  // 2 KB, contiguous chunk
    {
        const float* src = Bm + ((size_t)b * L_ + t0) * DS_;
        s_Bm[tid]       = src[tid];
        s_Bm[256 + tid] = src[256 + tid];
    }
    float a[DS_];
    #pragma unroll
    for (int qq = 0; qq < 4; ++qq)
        *(float4*)&a[qq * 4] = *(const float4*)(A + (size_t)d * DS_ + qq * 4);
    __syncthreads();

    const float* dtp = dt + ((size_t)b * L_ + t0) * DI_ + d;
    const float* xcp = xc + ((size_t)b * L_ + t0) * DI_ + d;

    float h[DS_] = {};
    float P[DS_];
    #pragma unroll
    for (int s = 0; s < DS_; ++s) P[s] = 1.0f;

    float dtv = dtp[0], xcv = xcp[0];
    #pragma unroll 4
    for (int t = 0; t < TL_; ++t) {
        float dtv_n = 0.f, xcv_n = 0.f;
        if (t + 1 < TL_) {
            dtv_n = dtp[(size_t)(t + 1) * DI_];
            xcv_n = xcp[(size_t)(t + 1) * DI_];
        }
        const float dx = dtv * xcv;
        #pragma unroll
        for (int qq = 0; qq < 4; ++qq) {
            const float4 bm = *(const float4*)&s_Bm[t * DS_ + qq * 4];
            #pragma unroll
            for (int i = 0; i < 4; ++i) {
                const int s = qq * 4 + i;
                const float bv = (i == 0) ? bm.x : (i == 1) ? bm.y : (i == 2) ? bm.z : bm.w;
                const float dA = __expf(dtv * a[s]);
                P[s] *= dA;
                h[s] = fmaf(dA, h[s], dx * bv);
            }
        }
        dtv = dtv_n; xcv = xcv_n;
    }
    const size_t o0 = (((size_t)b * NCH_ + j) * DS_) * DI_ + d;
    #pragma unroll
    for (int s = 0; s < DS_; ++s) {
        Pc[o0 + (size_t)s * DI_] = P[s];
        Hc[o0 + (size_t)s * DI_] = h[s];
    }
}

__global__ __launch_bounds__(256) void scan_combine(
    const float* __restrict__ Pc, float* __restrict__ Hc)
{
    const size_t idx = (size_t)blockIdx.x * 256 + threadIdx.x;   // over BN*DS*DI
    const size_t b   = idx / (DS_ * DI_);
    const size_t rem = idx % (DS_ * DI_);
    const size_t base   = b * ((size_t)NCH_ * DS_ * DI_) + rem;
    const size_t stride = (size_t)DS_ * DI_;
    float h = 0.f;
    #pragma unroll
    for (int j = 0; j < NCH_; ++j) {
        const size_t o = base + (size_t)j * stride;
        const float P  = Pc[o];
        const float hl = Hc[o];
        Hc[o] = h;                 // incoming state for chunk j
        h = fmaf(P, h, hl);
    }
}

__global__ __launch_bounds__(256) void scan_part2(
    const float* __restrict__ dt, const float* __restrict__ xc,
    const float* __restrict__ gate,
    const float* __restrict__ Bm, const float* __restrict__ Cm,
    const float* __restrict__ A, const float* __restrict__ Dp,
    const float* __restrict__ Hin, unsigned short* __restrict__ ygb)
{
    const int tid = threadIdx.x;
    const int d   = blockIdx.x * 256 + tid;
    const int b   = blockIdx.y;
    const int j   = blockIdx.z;
    const int t0  = j * TL_;

    __shared__ float s_Bm[TL_ * DS_];
    __shared__ float s_Cm[TL_ * DS_];
    {
        const float* bsrc = Bm + ((size_t)b * L_ + t0) * DS_;
        const float* csrc = Cm + ((size_t)b * L_ + t0) * DS_;
        s_Bm[tid]       = bsrc[tid];
        s_Bm[256 + tid] = bsrc[256 + tid];
        s_Cm[tid]       = csrc[tid];
        s_Cm[256 + tid] = csrc[256 + tid];
    }
    float a[DS_];
    #pragma unroll
    for (int qq = 0; qq < 4; ++qq)
        *(float4*)&a[qq * 4] = *(const float4*)(A + (size_t)d * DS_ + qq * 4);
    const float dp = Dp[d];

    float h[DS_];
    {
        const size_t o0 = (((size_t)b * NCH_ + j) * DS_) * DI_ + d;
        #pragma unroll
        for (int s = 0; s < DS_; ++s) h[s] = Hin[o0 + (size_t)s * DI_];
    }
    __syncthreads();

    const size_t rbase = ((size_t)b * L_ + t0) * DI_ + d;
    const float* dtp = dt   + rbase;
    const float* xcp = xc   + rbase;
    const float* gvp = gate + rbase;
    unsigned short* yp = ygb + rbase;

    float dtv = dtp[0], xcv = xcp[0], gv = gvp[0];
    #pragma unroll 4
    for (int t = 0; t < TL_; ++t) {
        float dtv_n = 0.f, xcv_n = 0.f, gv_n = 0.f;
        if (t + 1 < TL_) {
            dtv_n = dtp[(size_t)(t + 1) * DI_];
            xcv_n = xcp[(size_t)(t + 1) * DI_];
            gv_n  = gvp[(size_t)(t + 1) * DI_];
        }
        const float dx = dtv * xcv;
        float y0 = 0.f, y1 = 0.f, y2 = 0.f, y3 = 0.f;
        #pragma unroll
        for (int qq = 0; qq < 4; ++qq) {
            const float4 bm = *(const float4*)&s_Bm[t * DS_ + qq * 4];
            const float4 cm = *(const float4*)&s_Cm[t * DS_ + qq * 4];
            #pragma unroll
            for (int i = 0; i < 4; ++i) {
                const int s = qq * 4 + i;
                const float bv = (i == 0) ? bm.x : (i == 1) ? bm.y : (i == 2) ? bm.z : bm.w;
                const float cv = (i == 0) ? cm.x : (i == 1) ? cm.y : (i == 2) ? cm.z : cm.w;
                const float dA = __expf(dtv * a[s]);
                h[s] = fmaf(dA, h[s], dx * bv);
                if (i == 0) y0 = fmaf(h[s], cv, y0);
                else if (i == 1) y1 = fmaf(h[s], cv, y1);
                else if (i == 2) y2 = fmaf(h[s], cv, y2);
                else y3 = fmaf(h[s], cv, y3);
            }
        }
        float y = (y0 + y1) + (y2 + y3);
        y = fmaf(xcv, dp, y);
        const float r = y * (gv / (1.0f + __expf(-gv)));
        yp[(size_t)t * DI_] = f2b(r);
        dtv = dtv_n; xcv = xcv_n; gv = gv_n;
    }
}

// ---------------------------------------------------------------------------
extern "C" void kernel_launch(void* const* d_in, const int* in_sizes, int n_in,
                              void* d_out, int out_size, void* d_ws, size_t ws_size,
                              hipStream_t stream)
{
    const float* x      = (const float*)d_in[0];
    const float* in_w   = (const float*)d_in[1];
    const float* in_b   = (const float*)d_in[2];
    const float* conv_w = (const float*)d_in[3];
    const float* conv_b = (const float*)d_in[4];
    const float* A      = (const float*)d_in[5];
    const float* Dp     = (const float*)d_in[6];
    const float* B_w    = (const float*)d_in[7];
    const float* B_b    = (const float*)d_in[8];
    const float* C_w    = (const float*)d_in[9];
    const float* C_b    = (const float*)d_in[10];
    const float* dt_w   = (const float*)d_in[11];
    const float* dt_b   = (const float*)d_in[12];
    const float* out_w  = (const float*)d_in[13];
    const float* out_b  = (const float*)d_in[14];
    float* out = (float*)d_out;

    // ---- workspace layout (aliased; peak 84.25 MB) ----
    float* xz   = (float*)d_ws;                 // [M][DI] fp32, 16MB (dead after conv)
    float* gate = xz   + (size_t)M_ * DI_;      // [M][DI] fp32, 16MB
    float* xc   = gate + (size_t)M_ * DI_;      // [M][DI] fp32, 16MB
    float* dtb  = xc   + (size_t)M_ * DI_;      // [M][DI] fp32, 16MB
    float* Bm   = dtb  + (size_t)M_ * DI_;      // [M][16]
    float* Cm   = Bm   + (size_t)M_ * DS_;      // [M][16]
    unsigned short* w1  = (unsigned short*)(Cm + (size_t)M_ * DS_); // 4M bf16 (8MB)
    unsigned short* xb  = w1  + (size_t)4 * 1024 * 1024;            // 2M bf16 (4MB)
    unsigned short* xcb = xb  + (size_t)2 * 1024 * 1024;            // 4M bf16 (8MB)
    unsigned short* ygb = xcb;                  // alias (xcb dead after dt GEMM)
    float* Pc = xz;                             // alias xz (dead after conv), 8MB
    float* Hc = xz + (size_t)BN_ * NCH_ * DS_ * DI_;   // second half of xz, 8MB

    // 1) bf16 shadows of x and in_w^T
    cast_bf16<<<(M_ * DM_ / 4 + 255) / 256, 256, 0, stream>>>(x, xb, M_ * DM_);
    transpose_cast<<<dim3(2 * DI_ / 32, DM_ / 32), 256, 0, stream>>>(in_w, w1, DM_, 2 * DI_);

    // 2) [xz | gate] = x @ in_w + in_b   (M=2048, N=4096, K=1024, split at 2048)
    gemm_mfma<<<dim3(2 * DI_ / 128, M_ / 128), 256, 0, stream>>>(
        xb, w1, in_b, xz, gate, M_, 2 * DI_, DM_, DI_, 0);

    // 3) depthwise conv + silu (fp32 + bf16 outputs)
    conv_silu<<<(BN_ * L_ * DI_) / 256, 256, 0, stream>>>(xz, conv_w, conv_b, xc, xcb);

    // 4) Bm, Cm projections
    bc_proj<<<M_, 256, 0, stream>>>(xc, B_w, B_b, C_w, C_b, Bm, Cm);

    // 5) dt = softplus(x_conv @ dt_w + dt_b)   (M=2048, N=2048, K=2048)
    transpose_cast<<<dim3(DI_ / 32, DI_ / 32), 256, 0, stream>>>(dt_w, w1, DI_, DI_);
    gemm_mfma<<<dim3(DI_ / 128, M_ / 128), 256, 0, stream>>>(
        xcb, w1, dt_b, dtb, dtb, M_, DI_, DI_, DI_, 1);

    // 6) out_w^T (w1 free again after dt GEMM)
    transpose_cast<<<dim3(DM_ / 32, DI_ / 32), 256, 0, stream>>>(out_w, w1, DI_, DM_);

    // 7) chunked scan: part1 -> combine -> part2 (writes bf16 ygb)
    scan_part1<<<dim3(DI_ / 256, BN_, NCH_), 256, 0, stream>>>(
        dtb, xc, Bm, A, Pc, Hc);
    scan_combine<<<(BN_ * DI_ * DS_) / 256, 256, 0, stream>>>(Pc, Hc);
    scan_part2<<<dim3(DI_ / 256, BN_, NCH_), 256, 0, stream>>>(
        dtb, xc, gate, Bm, Cm, A, Dp, Hc, ygb);

    // 8) out = yg @ out_w + out_b   (M=2048, N=1024, K=2048)
    gemm_mfma<<<dim3(DM_ / 128, M_ / 128), 256, 0, stream>>>(
        ygb, w1, out_b, out, out, M_, DM_, DI_, DM_, 0);
}

// Round 7
// 221.244 us; speedup vs baseline: 5.9093x; 1.1013x over previous
//
#include <hip/hip_runtime.h>
#include <hip/hip_bf16.h>
#include <math.h>

// Problem constants: BN=2, L=1024, DM=1024, D_STATE=16, D_CONV=4, EXPAND=2,
// D_INNER=2048. M = BN*L = 2048.
#define BN_   2
#define L_    1024
#define DM_   1024
#define DS_   16
#define DI_   2048
#define M_    (BN_ * L_)
#define NBC_  2176           // dt(2048) + Bm(16) + Cm(16) + pad(96), 17*128

typedef __attribute__((ext_vector_type(8))) short short8;
typedef __attribute__((ext_vector_type(4))) float f32x4;

__device__ __forceinline__ unsigned short f2b(float f) {
    union { float f; unsigned u; } x; x.f = f;
    unsigned r = x.u + 0x7fffu + ((x.u >> 16) & 1u);   // RNE
    return (unsigned short)(r >> 16);
}
__device__ __forceinline__ float b2f(unsigned short u) {
    union { unsigned u; float f; } x; x.u = ((unsigned)u) << 16; return x.f;
}

__device__ __forceinline__ void gload_lds16(const unsigned short* g, unsigned short* l) {
    __builtin_amdgcn_global_load_lds(
        (const __attribute__((address_space(1))) void*)g,
        (__attribute__((address_space(3))) void*)l, 16, 0, 0);
}

// ---------------------------------------------------------------------------
// elementwise fp32 -> bf16 cast (n multiple of 4)
// ---------------------------------------------------------------------------
__global__ __launch_bounds__(256) void cast_bf16(
    const float* __restrict__ in, unsigned short* __restrict__ out, int n)
{
    const int i = (blockIdx.x * 256 + threadIdx.x) * 4;
    if (i >= n) return;
    float4 v = *(const float4*)(in + i);
    ushort4 o; o.x = f2b(v.x); o.y = f2b(v.y); o.z = f2b(v.z); o.w = f2b(v.w);
    *(ushort4*)(out + i) = o;
}

// ---------------------------------------------------------------------------
// transpose + cast: in fp32 [R][C] -> out bf16 [C][R].  R,C multiples of 32.
// ---------------------------------------------------------------------------
__global__ __launch_bounds__(256) void transpose_cast(
    const float* __restrict__ in, unsigned short* __restrict__ out, int R, int C)
{
    __shared__ float t[32][33];
    const int bx = blockIdx.x * 32;   // C dir
    const int by = blockIdx.y * 32;   // R dir
    const int tx = threadIdx.x & 31;
    const int ty = (threadIdx.x >> 5) * 4;
    #pragma unroll
    for (int j = 0; j < 4; ++j)
        t[ty + j][tx] = in[(size_t)(by + ty + j) * C + bx + tx];
    __syncthreads();
    #pragma unroll
    for (int j = 0; j < 4; ++j)
        out[(size_t)(bx + ty + j) * R + by + tx] = f2b(t[tx][ty + j]);
}

// ---------------------------------------------------------------------------
// pack B_w / C_w transposed into w2 rows 2048..2079 ([N][K] layout).
// w2[2048+s][k] = B_w[k][s]; w2[2064+s][k] = C_w[k][s].
// ---------------------------------------------------------------------------
__global__ __launch_bounds__(256) void bc_pack(
    const float* __restrict__ Bw, const float* __restrict__ Cw,
    unsigned short* __restrict__ w2)
{
    const int idx = blockIdx.x * 256 + threadIdx.x;   // 32*2048
    const int r = idx >> 11;        // 0..31
    const int k = idx & 2047;
    const float* src = (r < 16) ? Bw : Cw;
    w2[(size_t)(2048 + r) * 2048 + k] = f2b(src[k * 16 + (r & 15)]);
}

// ---------------------------------------------------------------------------
// bf16 MFMA GEMM, m97 structure (single 32 KiB LDS buffer -> 4-5 blocks/CU)
// + read-side XOR swizzle (round-6, conflict-free) + XCD-aware bijective
// block swizzle (T1, column-chunked). 128x128 tile, BK=64, 4 waves (2x2).
//   MODE 0: bf16 output, column-split at NS -> U0 | U1        (in_proj)
//   MODE 1: fp32; c<2048 softplus->F0; 2048..2063 ->F1(+b1);
//           2064..2079 ->F2(+b2); higher cols (pad) discarded  (dt+B+C)
//   MODE 2: fp32 single output F0                              (out_proj)
// ---------------------------------------------------------------------------
template<int MODE>
__global__ __launch_bounds__(256) void gemm_mfma(
    const unsigned short* __restrict__ A,   // [M][K] bf16
    const unsigned short* __restrict__ Bt,  // [N][K] bf16
    const float* __restrict__ b0, const float* __restrict__ b1,
    const float* __restrict__ b2,
    float* __restrict__ F0, float* __restrict__ F1, float* __restrict__ F2,
    unsigned short* __restrict__ U0, unsigned short* __restrict__ U1,
    int M, int N, int K, int NS)
{
    __shared__ unsigned short Asl[128 * 64];
    __shared__ unsigned short Bsl[128 * 64];

    const int tid  = threadIdx.x;
    const int wave = tid >> 6;
    const int lane = tid & 63;

    // XCD-aware bijective swizzle (all call sites have nwg % 8 == 0).
    // Column-chunked: each XCD owns a contiguous set of column-panels.
    const int gx  = gridDim.x, gy = gridDim.y;
    const int bid = blockIdx.y * gx + blockIdx.x;
    const int q   = (gx * gy) >> 3;
    const int nb  = (bid & 7) * q + (bid >> 3);
    const int by  = nb % gy;
    const int bx  = nb / gy;

    const int row0 = by * 128;
    const int col0 = bx * 128;
    const int wr   = (wave >> 1) * 64;
    const int wc   = (wave & 1) * 64;

    const int srow = lane >> 3;                          // row within 8-row chunk
    const int scol = ((lane & 7) ^ (lane >> 3)) * 8;     // pre-swizzled source col

    f32x4 acc[4][4];
    #pragma unroll
    for (int m = 0; m < 4; ++m)
        #pragma unroll
        for (int n = 0; n < 4; ++n)
            acc[m][n] = (f32x4){0.f, 0.f, 0.f, 0.f};

    for (int kt = 0; kt < K; kt += 64) {
        #pragma unroll
        for (int i = 0; i < 4; ++i) {
            const int chunk = wave * 4 + i;              // 16 chunks x 8 rows
            gload_lds16(A  + (size_t)(row0 + chunk * 8 + srow) * K + kt + scol,
                        Asl + chunk * 512);
            gload_lds16(Bt + (size_t)(col0 + chunk * 8 + srow) * K + kt + scol,
                        Bsl + chunk * 512);
        }
        __syncthreads();   // vmcnt(0) drain: tile visible

        short8 af[4][2], bf[4][2];
        const int lrow  = lane & 15;
        const int xsw   = (lane & 7) * 8;                // read-side XOR (row&7)*8
        const int cbase = (lane >> 4) * 8;
        #pragma unroll
        for (int m = 0; m < 4; ++m)
            #pragma unroll
            for (int kk = 0; kk < 2; ++kk)
                af[m][kk] = *(const short8*)
                    &Asl[(wr + m * 16 + lrow) * 64 + ((kk * 32 + cbase) ^ xsw)];
        #pragma unroll
        for (int n = 0; n < 4; ++n)
            #pragma unroll
            for (int kk = 0; kk < 2; ++kk)
                bf[n][kk] = *(const short8*)
                    &Bsl[(wc + n * 16 + lrow) * 64 + ((kk * 32 + cbase) ^ xsw)];

        #pragma unroll
        for (int m = 0; m < 4; ++m)
            #pragma unroll
            for (int n = 0; n < 4; ++n) {
                acc[m][n] = __builtin_amdgcn_mfma_f32_16x16x32_bf16(
                    af[m][0], bf[n][0], acc[m][n], 0, 0, 0);
                acc[m][n] = __builtin_amdgcn_mfma_f32_16x16x32_bf16(
                    af[m][1], bf[n][1], acc[m][n], 0, 0, 0);
            }
        __syncthreads();   // tile consumed, safe to restage
    }

    // epilogue: C/D layout col=lane&15, row=(lane>>4)*4+j
    const int crow = (lane >> 4) * 4;
    const int ccol = lane & 15;
    #pragma unroll
    for (int m = 0; m < 4; ++m)
        #pragma unroll
        for (int n = 0; n < 4; ++n) {
            const int c = col0 + wc + n * 16 + ccol;
            if (MODE == 0) {
                const float bv = b0[c];
                unsigned short* dst = (c < NS) ? (U0 + c) : (U1 + (c - NS));
                #pragma unroll
                for (int j = 0; j < 4; ++j) {
                    const int r = row0 + wr + m * 16 + crow + j;
                    dst[(size_t)r * NS] = f2b(acc[m][n][j] + bv);
                }
            } else if (MODE == 1) {
                if (c < 2048) {
                    const float bv = b0[c];
                    #pragma unroll
                    for (int j = 0; j < 4; ++j) {
                        const int r = row0 + wr + m * 16 + crow + j;
                        float v = acc[m][n][j] + bv;
                        v = (v > 20.0f) ? v : log1pf(__expf(v));
                        F0[(size_t)r * 2048 + c] = v;
                    }
                } else if (c < 2064) {
                    const float bv = b1[c - 2048];
                    #pragma unroll
                    for (int j = 0; j < 4; ++j) {
                        const int r = row0 + wr + m * 16 + crow + j;
                        F1[(size_t)r * 16 + (c - 2048)] = acc[m][n][j] + bv;
                    }
                } else if (c < 2080) {
                    const float bv = b2[c - 2064];
                    #pragma unroll
                    for (int j = 0; j < 4; ++j) {
                        const int r = row0 + wr + m * 16 + crow + j;
                        F2[(size_t)r * 16 + (c - 2064)] = acc[m][n][j] + bv;
                    }
                }   // pad columns: discard
            } else {
                const float bv = b0[c];
                #pragma unroll
                for (int j = 0; j < 4; ++j) {
                    const int r = row0 + wr + m * 16 + crow + j;
                    F0[(size_t)r * NS + c] = acc[m][n][j] + bv;
                }
            }
        }
}

// ---------------------------------------------------------------------------
// Depthwise conv (window 4, SAME: taps t-1..t+2) + bias + SiLU.
// Reads bf16 xzb [M][DI]; writes fp32 xc and bf16 xcb.
// ---------------------------------------------------------------------------
__global__ __launch_bounds__(256) void conv_silu(
    const unsigned short* __restrict__ xzb, const float* __restrict__ cw,
    const float* __restrict__ cb, float* __restrict__ xc,
    unsigned short* __restrict__ xcb)
{
    const int idx = blockIdx.x * 256 + threadIdx.x;
    if (idx >= BN_ * L_ * DI_) return;
    const int d = idx & (DI_ - 1);
    const int t = (idx / DI_) & (L_ - 1);
    const int b = idx / (DI_ * L_);

    float acc = cb[d];
    #pragma unroll
    for (int w = 0; w < 4; ++w) {
        const int tt = t + w - 1;
        if (tt >= 0 && tt < L_)
            acc = fmaf(b2f(xzb[((size_t)(b * L_ + tt)) * DI_ + d]), cw[w * DI_ + d], acc);
    }
    const float s = acc / (1.0f + __expf(-acc));
    xc[idx]  = s;
    xcb[idx] = f2b(s);
}

// ---------------------------------------------------------------------------
// Chunked selective scan, one CHANNEL per lane, 16 states in registers.
// ---------------------------------------------------------------------------
#define NCH_ 32
#define TL_  (L_ / NCH_)   // 32

__global__ __launch_bounds__(256) void scan_part1(
    const float* __restrict__ dt, const float* __restrict__ xc,
    const float* __restrict__ Bm, const float* __restrict__ A,
    float* __restrict__ Pc, float* __restrict__ Hc)
{
    const int tid = threadIdx.x;
    const int d   = blockIdx.x * 256 + tid;
    const int b   = blockIdx.y;
    const int j   = blockIdx.z;
    const int t0  = j * TL_;

    __shared__ float s_Bm[TL_ * DS_];                  // 2 KB
    {
        const float* src = Bm + ((size_t)b * L_ + t0) * DS_;
        s_Bm[tid]       = src[tid];
        s_Bm[256 + tid] = src[256 + tid];
    }
    float a[DS_];
    #pragma unroll
    for (int qq = 0; qq < 4; ++qq)
        *(float4*)&a[qq * 4] = *(const float4*)(A + (size_t)d * DS_ + qq * 4);
    __syncthreads();

    const float* dtp = dt + ((size_t)b * L_ + t0) * DI_ + d;
    const float* xcp = xc + ((size_t)b * L_ + t0) * DI_ + d;

    float h[DS_] = {};
    float P[DS_];
    #pragma unroll
    for (int s = 0; s < DS_; ++s) P[s] = 1.0f;

    float dtv = dtp[0], xcv = xcp[0];
    #pragma unroll 4
    for (int t = 0; t < TL_; ++t) {
        float dtv_n = 0.f, xcv_n = 0.f;
        if (t + 1 < TL_) {
            dtv_n = dtp[(size_t)(t + 1) * DI_];
            xcv_n = xcp[(size_t)(t + 1) * DI_];
        }
        const float dx = dtv * xcv;
        #pragma unroll
        for (int qq = 0; qq < 4; ++qq) {
            const float4 bm = *(const float4*)&s_Bm[t * DS_ + qq * 4];
            #pragma unroll
            for (int i = 0; i < 4; ++i) {
                const int s = qq * 4 + i;
                const float bv = (i == 0) ? bm.x : (i == 1) ? bm.y : (i == 2) ? bm.z : bm.w;
                const float dA = __expf(dtv * a[s]);
                P[s] *= dA;
                h[s] = fmaf(dA, h[s], dx * bv);
            }
        }
        dtv = dtv_n; xcv = xcv_n;
    }
    const size_t o0 = (((size_t)b * NCH_ + j) * DS_) * DI_ + d;
    #pragma unroll
    for (int s = 0; s < DS_; ++s) {
        Pc[o0 + (size_t)s * DI_] = P[s];
        Hc[o0 + (size_t)s * DI_] = h[s];
    }
}

__global__ __launch_bounds__(256) void scan_combine(
    const float* __restrict__ Pc, float* __restrict__ Hc)
{
    const size_t idx = (size_t)blockIdx.x * 256 + threadIdx.x;   // over BN*DS*DI
    const size_t b   = idx / (DS_ * DI_);
    const size_t rem = idx % (DS_ * DI_);
    const size_t base   = b * ((size_t)NCH_ * DS_ * DI_) + rem;
    const size_t stride = (size_t)DS_ * DI_;
    float h = 0.f;
    #pragma unroll
    for (int j = 0; j < NCH_; ++j) {
        const size_t o = base + (size_t)j * stride;
        const float P  = Pc[o];
        const float hl = Hc[o];
        Hc[o] = h;                 // incoming state for chunk j
        h = fmaf(P, h, hl);
    }
}

__global__ __launch_bounds__(256) void scan_part2(
    const float* __restrict__ dt, const float* __restrict__ xc,
    const unsigned short* __restrict__ gate,     // bf16
    const float* __restrict__ Bm, const float* __restrict__ Cm,
    const float* __restrict__ A, const float* __restrict__ Dp,
    const float* __restrict__ Hin, unsigned short* __restrict__ ygb)
{
    const int tid = threadIdx.x;
    const int d   = blockIdx.x * 256 + tid;
    const int b   = blockIdx.y;
    const int j   = blockIdx.z;
    const int t0  = j * TL_;

    __shared__ float s_Bm[TL_ * DS_];
    __shared__ float s_Cm[TL_ * DS_];
    {
        const float* bsrc = Bm + ((size_t)b * L_ + t0) * DS_;
        const float* csrc = Cm + ((size_t)b * L_ + t0) * DS_;
        s_Bm[tid]       = bsrc[tid];
        s_Bm[256 + tid] = bsrc[256 + tid];
        s_Cm[tid]       = csrc[tid];
        s_Cm[256 + tid] = csrc[256 + tid];
    }
    float a[DS_];
    #pragma unroll
    for (int qq = 0; qq < 4; ++qq)
        *(float4*)&a[qq * 4] = *(const float4*)(A + (size_t)d * DS_ + qq * 4);
    const float dp = Dp[d];

    float h[DS_];
    {
        const size_t o0 = (((size_t)b * NCH_ + j) * DS_) * DI_ + d;
        #pragma unroll
        for (int s = 0; s < DS_; ++s) h[s] = Hin[o0 + (size_t)s * DI_];
    }
    __syncthreads();

    const size_t rbase = ((size_t)b * L_ + t0) * DI_ + d;
    const float* dtp = dt   + rbase;
    const float* xcp = xc   + rbase;
    const unsigned short* gvp = gate + rbase;
    unsigned short* yp = ygb + rbase;

    float dtv = dtp[0], xcv = xcp[0], gv = b2f(gvp[0]);
    #pragma unroll 4
    for (int t = 0; t < TL_; ++t) {
        float dtv_n = 0.f, xcv_n = 0.f, gv_n = 0.f;
        if (t + 1 < TL_) {
            dtv_n = dtp[(size_t)(t + 1) * DI_];
            xcv_n = xcp[(size_t)(t + 1) * DI_];
            gv_n  = b2f(gvp[(size_t)(t + 1) * DI_]);
        }
        const float dx = dtv * xcv;
        float y0 = 0.f, y1 = 0.f, y2 = 0.f, y3 = 0.f;
        #pragma unroll
        for (int qq = 0; qq < 4; ++qq) {
            const float4 bm = *(const float4*)&s_Bm[t * DS_ + qq * 4];
            const float4 cm = *(const float4*)&s_Cm[t * DS_ + qq * 4];
            #pragma unroll
            for (int i = 0; i < 4; ++i) {
                const int s = qq * 4 + i;
                const float bv = (i == 0) ? bm.x : (i == 1) ? bm.y : (i == 2) ? bm.z : bm.w;
                const float cv = (i == 0) ? cm.x : (i == 1) ? cm.y : (i == 2) ? cm.z : cm.w;
                const float dA = __expf(dtv * a[s]);
                h[s] = fmaf(dA, h[s], dx * bv);
                if (i == 0) y0 = fmaf(h[s], cv, y0);
                else if (i == 1) y1 = fmaf(h[s], cv, y1);
                else if (i == 2) y2 = fmaf(h[s], cv, y2);
                else y3 = fmaf(h[s], cv, y3);
            }
        }
        float y = (y0 + y1) + (y2 + y3);
        y = fmaf(xcv, dp, y);
        const float r = y * (gv / (1.0f + __expf(-gv)));
        yp[(size_t)t * DI_] = f2b(r);
        dtv = dtv_n; xcv = xcv_n; gv = gv_n;
    }
}

// ---------------------------------------------------------------------------
extern "C" void kernel_launch(void* const* d_in, const int* in_sizes, int n_in,
                              void* d_out, int out_size, void* d_ws, size_t ws_size,
                              hipStream_t stream)
{
    const float* x      = (const float*)d_in[0];
    const float* in_w   = (const float*)d_in[1];
    const float* in_b   = (const float*)d_in[2];
    const float* conv_w = (const float*)d_in[3];
    const float* conv_b = (const float*)d_in[4];
    const float* A      = (const float*)d_in[5];
    const float* Dp     = (const float*)d_in[6];
    const float* B_w    = (const float*)d_in[7];
    const float* B_b    = (const float*)d_in[8];
    const float* C_w    = (const float*)d_in[9];
    const float* C_b    = (const float*)d_in[10];
    const float* dt_w   = (const float*)d_in[11];
    const float* dt_b   = (const float*)d_in[12];
    const float* out_w  = (const float*)d_in[13];
    const float* out_b  = (const float*)d_in[14];
    float* out = (float*)d_out;

    // ---- workspace layout (aliased; peak 80.75 MB) ----
    float* xc   = (float*)d_ws;                    // [M][DI] fp32, 16MB
    float* dtb  = xc  + (size_t)M_ * DI_;          // [M][DI] fp32, 16MB
    float* Bm   = dtb + (size_t)M_ * DI_;          // [M][16] 128KB
    float* Cm   = Bm  + (size_t)M_ * DS_;          // [M][16] 128KB
    unsigned short* w3  = (unsigned short*)(Cm + (size_t)M_ * DS_); // out_w^T  4MB
    unsigned short* w1  = w3  + (size_t)DM_ * DI_;                  // in_w^T   8MB
    unsigned short* xb  = w1  + (size_t)2 * DI_ * DM_;              // x bf16   4MB
    unsigned short* w2  = xb  + (size_t)M_ * DM_;                   // dtBC^T   8.5MB
    unsigned short* xcb = w2  + (size_t)NBC_ * DI_;                 // xc bf16  8MB
    unsigned short* xzb = xcb + (size_t)M_ * DI_;                   // xz bf16  8MB
    unsigned short* gtb = xzb + (size_t)M_ * DI_;                   // gate bf16 8MB
    unsigned short* ygb = xcb;                     // alias (xcb dead after dtBC GEMM)
    float* Pc = (float*)w1;                        // 8MB over w1 (dead after in_proj)
    float* Hc = Pc + (size_t)BN_ * NCH_ * DS_ * DI_;  // 8MB over xb + w2 head (dead)

    // 1) bf16 shadows: x, in_w^T
    cast_bf16<<<(M_ * DM_ / 4 + 255) / 256, 256, 0, stream>>>(x, xb, M_ * DM_);
    transpose_cast<<<dim3(2 * DI_ / 32, DM_ / 32), 256, 0, stream>>>(in_w, w1, DM_, 2 * DI_);

    // 2) [xzb | gtb] = bf16(x @ in_w + in_b)   (M=2048, N=4096, K=1024)
    gemm_mfma<0><<<dim3(2 * DI_ / 128, M_ / 128), 256, 0, stream>>>(
        xb, w1, in_b, nullptr, nullptr,
        nullptr, nullptr, nullptr, xzb, gtb, M_, 2 * DI_, DM_, DI_);

    // 3) depthwise conv + silu (fp32 xc + bf16 xcb)
    conv_silu<<<(BN_ * L_ * DI_) / 256, 256, 0, stream>>>(xzb, conv_w, conv_b, xc, xcb);

    // 4) fused dt/B/C weights: w2 = [dt_w | B_w | C_w]^T
    transpose_cast<<<dim3(DI_ / 32, DI_ / 32), 256, 0, stream>>>(dt_w, w2, DI_, DI_);
    bc_pack<<<(32 * 2048) / 256, 256, 0, stream>>>(B_w, C_w, w2);

    // 5) dtb = softplus(xc @ dt_w + dt_b); Bm = xc@B_w+B_b; Cm = xc@C_w+C_b
    gemm_mfma<1><<<dim3(NBC_ / 128, M_ / 128), 256, 0, stream>>>(
        xcb, w2, dt_b, B_b, C_b,
        dtb, Bm, Cm, nullptr, nullptr, M_, NBC_, DI_, NBC_);

    // 6) out_w^T (dedicated buffer, no alias hazard)
    transpose_cast<<<dim3(DM_ / 32, DI_ / 32), 256, 0, stream>>>(out_w, w3, DI_, DM_);

    // 7) chunked scan: part1 -> combine -> part2 (writes bf16 ygb)
    scan_part1<<<dim3(DI_ / 256, BN_, NCH_), 256, 0, stream>>>(
        dtb, xc, Bm, A, Pc, Hc);
    scan_combine<<<(BN_ * DI_ * DS_) / 256, 256, 0, stream>>>(Pc, Hc);
    scan_part2<<<dim3(DI_ / 256, BN_, NCH_), 256, 0, stream>>>(
        dtb, xc, gtb, Bm, Cm, A, Dp, Hc, ygb);

    // 8) out = yg @ out_w + out_b   (M=2048, N=1024, K=2048)
    gemm_mfma<2><<<dim3(DM_ / 128, M_ / 128), 256, 0, stream>>>(
        ygb, w3, out_b, nullptr, nullptr,
        out, nullptr, nullptr, nullptr, nullptr, M_, DM_, DI_, DM_);
}

// Round 8
// 193.944 us; speedup vs baseline: 6.7411x; 1.1408x over previous
//
#include <hip/hip_runtime.h>
#include <hip/hip_bf16.h>
#include <math.h>

// Problem constants: BN=2, L=1024, DM=1024, D_STATE=16, D_CONV=4, EXPAND=2,
// D_INNER=2048. M = BN*L = 2048.
#define BN_   2
#define L_    1024
#define DM_   1024
#define DS_   16
#define DI_   2048
#define M_    (BN_ * L_)
#define NBC_  2176           // dt(2048) + Bm(16) + Cm(16) + pad(96), 17*128

typedef __attribute__((ext_vector_type(8))) short short8;
typedef __attribute__((ext_vector_type(4))) float f32x4;

__device__ __forceinline__ unsigned short f2b(float f) {
    union { float f; unsigned u; } x; x.f = f;
    unsigned r = x.u + 0x7fffu + ((x.u >> 16) & 1u);   // RNE
    return (unsigned short)(r >> 16);
}
__device__ __forceinline__ float b2f(unsigned short u) {
    union { unsigned u; float f; } x; x.u = ((unsigned)u) << 16; return x.f;
}

__device__ __forceinline__ void gload_lds16(const unsigned short* g, unsigned short* l) {
    __builtin_amdgcn_global_load_lds(
        (const __attribute__((address_space(1))) void*)g,
        (__attribute__((address_space(3))) void*)l, 16, 0, 0);
}

// ---------------------------------------------------------------------------
// elementwise fp32 -> bf16 cast (n multiple of 4)
// ---------------------------------------------------------------------------
__global__ __launch_bounds__(256) void cast_bf16(
    const float* __restrict__ in, unsigned short* __restrict__ out, int n)
{
    const int i = (blockIdx.x * 256 + threadIdx.x) * 4;
    if (i >= n) return;
    float4 v = *(const float4*)(in + i);
    ushort4 o; o.x = f2b(v.x); o.y = f2b(v.y); o.z = f2b(v.z); o.w = f2b(v.w);
    *(ushort4*)(out + i) = o;
}

// ---------------------------------------------------------------------------
// transpose + cast: in fp32 [R][C] -> out bf16 [C][R].  R,C multiples of 32.
// ---------------------------------------------------------------------------
__global__ __launch_bounds__(256) void transpose_cast(
    const float* __restrict__ in, unsigned short* __restrict__ out, int R, int C)
{
    __shared__ float t[32][33];
    const int bx = blockIdx.x * 32;   // C dir
    const int by = blockIdx.y * 32;   // R dir
    const int tx = threadIdx.x & 31;
    const int ty = (threadIdx.x >> 5) * 4;
    #pragma unroll
    for (int j = 0; j < 4; ++j)
        t[ty + j][tx] = in[(size_t)(by + ty + j) * C + bx + tx];
    __syncthreads();
    #pragma unroll
    for (int j = 0; j < 4; ++j)
        out[(size_t)(bx + ty + j) * R + by + tx] = f2b(t[tx][ty + j]);
}

// ---------------------------------------------------------------------------
// pack B_w / C_w transposed into w2 rows 2048..2079 ([N][K] layout).
// ---------------------------------------------------------------------------
__global__ __launch_bounds__(256) void bc_pack(
    const float* __restrict__ Bw, const float* __restrict__ Cw,
    unsigned short* __restrict__ w2)
{
    const int idx = blockIdx.x * 256 + threadIdx.x;   // 32*2048
    const int r = idx >> 11;        // 0..31
    const int k = idx & 2047;
    const float* src = (r < 16) ? Bw : Cw;
    w2[(size_t)(2048 + r) * 2048 + k] = f2b(src[k * 16 + (r & 15)]);
}

// ---------------------------------------------------------------------------
// bf16 MFMA GEMM, double-buffered, read-side XOR swizzle (conflict-free),
// XCD-aware bijective block swizzle. Tile BM x BN (BM,BN in {64,128}),
// BK=64, 4 waves (2x2), 16x16x32 frags, fp32 accumulate.
//   MODE 0: bf16 output, column-split at NS -> U0 | U1        (in_proj)
//   MODE 1: fp32; c<2048 softplus->F0; 2048..2063 ->F1(+b1);
//           2064..2079 ->F2(+b2); higher cols (pad) discarded  (dt+B+C)
//   MODE 2: fp32 single output F0                              (out_proj)
// ---------------------------------------------------------------------------
template<int BM, int BN, int MODE>
__global__ __launch_bounds__(256) void gemm_mfma(
    const unsigned short* __restrict__ A,   // [M][K] bf16
    const unsigned short* __restrict__ Bt,  // [N][K] bf16
    const float* __restrict__ b0, const float* __restrict__ b1,
    const float* __restrict__ b2,
    float* __restrict__ F0, float* __restrict__ F1, float* __restrict__ F2,
    unsigned short* __restrict__ U0, unsigned short* __restrict__ U1,
    int M, int N, int K, int NS)
{
    constexpr int MF  = BM / 32;   // m-frags per wave
    constexpr int NF  = BN / 32;   // n-frags per wave
    constexpr int ACW = BM / 32;   // A 8-row chunks staged per wave
    constexpr int BCW = BN / 32;   // B 8-row chunks staged per wave

    __shared__ unsigned short Asl[2][BM * 64];
    __shared__ unsigned short Bsl[2][BN * 64];

    const int tid  = threadIdx.x;
    const int wave = tid >> 6;
    const int lane = tid & 63;

    // XCD-aware bijective swizzle (all call sites have nwg % 8 == 0).
    const int gx  = gridDim.x, gy = gridDim.y;
    const int bid = blockIdx.y * gx + blockIdx.x;
    const int q   = (gx * gy) >> 3;
    const int nb  = (bid & 7) * q + (bid >> 3);
    const int by  = nb % gy;
    const int bx  = nb / gy;

    const int row0 = by * BM;
    const int col0 = bx * BN;
    const int wr   = (wave >> 1) * (BM / 2);
    const int wc   = (wave & 1) * (BN / 2);

    const int srow = lane >> 3;                          // row within 8-row chunk
    const int scol = ((lane & 7) ^ (lane >> 3)) * 8;     // pre-swizzled source col

    auto stage = [&](int buf, int kt) {
        #pragma unroll
        for (int i = 0; i < ACW; ++i) {
            const int ch = wave * ACW + i;
            gload_lds16(A + (size_t)(row0 + ch * 8 + srow) * K + kt + scol,
                        &Asl[buf][ch * 512]);
        }
        #pragma unroll
        for (int i = 0; i < BCW; ++i) {
            const int ch = wave * BCW + i;
            gload_lds16(Bt + (size_t)(col0 + ch * 8 + srow) * K + kt + scol,
                        &Bsl[buf][ch * 512]);
        }
    };

    f32x4 acc[MF][NF];
    #pragma unroll
    for (int m = 0; m < MF; ++m)
        #pragma unroll
        for (int n = 0; n < NF; ++n)
            acc[m][n] = (f32x4){0.f, 0.f, 0.f, 0.f};

    stage(0, 0);
    __syncthreads();

    const int nk = K >> 6;
    int cur = 0;
    for (int kt = 0; kt < nk; ++kt) {
        if (kt + 1 < nk) stage(cur ^ 1, (kt + 1) << 6);

        short8 af[MF][2], bf[NF][2];
        const int lrow  = lane & 15;
        const int xsw   = (lane & 7) * 8;                // read-side XOR
        const int cbase = (lane >> 4) * 8;
        #pragma unroll
        for (int m = 0; m < MF; ++m)
            #pragma unroll
            for (int kk = 0; kk < 2; ++kk)
                af[m][kk] = *(const short8*)
                    &Asl[cur][(wr + m * 16 + lrow) * 64 + ((kk * 32 + cbase) ^ xsw)];
        #pragma unroll
        for (int n = 0; n < NF; ++n)
            #pragma unroll
            for (int kk = 0; kk < 2; ++kk)
                bf[n][kk] = *(const short8*)
                    &Bsl[cur][(wc + n * 16 + lrow) * 64 + ((kk * 32 + cbase) ^ xsw)];

        #pragma unroll
        for (int m = 0; m < MF; ++m)
            #pragma unroll
            for (int n = 0; n < NF; ++n) {
                acc[m][n] = __builtin_amdgcn_mfma_f32_16x16x32_bf16(
                    af[m][0], bf[n][0], acc[m][n], 0, 0, 0);
                acc[m][n] = __builtin_amdgcn_mfma_f32_16x16x32_bf16(
                    af[m][1], bf[n][1], acc[m][n], 0, 0, 0);
            }
        __syncthreads();   // drains prefetch vmcnt + protects cur from overwrite
        cur ^= 1;
    }

    // epilogue: C/D layout col=lane&15, row=(lane>>4)*4+j
    const int crow = (lane >> 4) * 4;
    const int ccol = lane & 15;
    #pragma unroll
    for (int m = 0; m < MF; ++m)
        #pragma unroll
        for (int n = 0; n < NF; ++n) {
            const int c = col0 + wc + n * 16 + ccol;
            if (MODE == 0) {
                const float bv = b0[c];
                unsigned short* dst = (c < NS) ? (U0 + c) : (U1 + (c - NS));
                #pragma unroll
                for (int j = 0; j < 4; ++j) {
                    const int r = row0 + wr + m * 16 + crow + j;
                    dst[(size_t)r * NS] = f2b(acc[m][n][j] + bv);
                }
            } else if (MODE == 1) {
                if (c < 2048) {
                    const float bv = b0[c];
                    #pragma unroll
                    for (int j = 0; j < 4; ++j) {
                        const int r = row0 + wr + m * 16 + crow + j;
                        float v = acc[m][n][j] + bv;
                        v = (v > 20.0f) ? v : log1pf(__expf(v));
                        F0[(size_t)r * 2048 + c] = v;
                    }
                } else if (c < 2064) {
                    const float bv = b1[c - 2048];
                    #pragma unroll
                    for (int j = 0; j < 4; ++j) {
                        const int r = row0 + wr + m * 16 + crow + j;
                        F1[(size_t)r * 16 + (c - 2048)] = acc[m][n][j] + bv;
                    }
                } else if (c < 2080) {
                    const float bv = b2[c - 2064];
                    #pragma unroll
                    for (int j = 0; j < 4; ++j) {
                        const int r = row0 + wr + m * 16 + crow + j;
                        F2[(size_t)r * 16 + (c - 2064)] = acc[m][n][j] + bv;
                    }
                }   // pad columns: discard
            } else {
                const float bv = b0[c];
                #pragma unroll
                for (int j = 0; j < 4; ++j) {
                    const int r = row0 + wr + m * 16 + crow + j;
                    F0[(size_t)r * NS + c] = acc[m][n][j] + bv;
                }
            }
        }
}

// ---------------------------------------------------------------------------
// Depthwise conv (window 4, SAME: taps t-1..t+2) + bias + SiLU.
// Reads bf16 xzb [M][DI]; writes bf16 xcb only.
// ---------------------------------------------------------------------------
__global__ __launch_bounds__(256) void conv_silu(
    const unsigned short* __restrict__ xzb, const float* __restrict__ cw,
    const float* __restrict__ cb, unsigned short* __restrict__ xcb)
{
    const int idx = blockIdx.x * 256 + threadIdx.x;
    if (idx >= BN_ * L_ * DI_) return;
    const int d = idx & (DI_ - 1);
    const int t = (idx / DI_) & (L_ - 1);
    const int b = idx / (DI_ * L_);

    float acc = cb[d];
    #pragma unroll
    for (int w = 0; w < 4; ++w) {
        const int tt = t + w - 1;
        if (tt >= 0 && tt < L_)
            acc = fmaf(b2f(xzb[((size_t)(b * L_ + tt)) * DI_ + d]), cw[w * DI_ + d], acc);
    }
    const float s = acc / (1.0f + __expf(-acc));
    xcb[idx] = f2b(s);
}

// ---------------------------------------------------------------------------
// Chunked selective scan, one CHANNEL per lane, 16 states in registers.
// xc is consumed as bf16 (same values the dt GEMM consumed).
// ---------------------------------------------------------------------------
#define NCH_ 32
#define TL_  (L_ / NCH_)   // 32

__global__ __launch_bounds__(256) void scan_part1(
    const float* __restrict__ dt, const unsigned short* __restrict__ xcb,
    const float* __restrict__ Bm, const float* __restrict__ A,
    float* __restrict__ Pc, float* __restrict__ Hc)
{
    const int tid = threadIdx.x;
    const int d   = blockIdx.x * 256 + tid;
    const int b   = blockIdx.y;
    const int j   = blockIdx.z;
    const int t0  = j * TL_;

    __shared__ float s_Bm[TL_ * DS_];                  // 2 KB
    {
        const float* src = Bm + ((size_t)b * L_ + t0) * DS_;
        s_Bm[tid]       = src[tid];
        s_Bm[256 + tid] = src[256 + tid];
    }
    float a[DS_];
    #pragma unroll
    for (int qq = 0; qq < 4; ++qq)
        *(float4*)&a[qq * 4] = *(const float4*)(A + (size_t)d * DS_ + qq * 4);
    __syncthreads();

    const float* dtp = dt + ((size_t)b * L_ + t0) * DI_ + d;
    const unsigned short* xcp = xcb + ((size_t)b * L_ + t0) * DI_ + d;

    float h[DS_] = {};
    float P[DS_];
    #pragma unroll
    for (int s = 0; s < DS_; ++s) P[s] = 1.0f;

    float dtv = dtp[0], xcv = b2f(xcp[0]);
    #pragma unroll 4
    for (int t = 0; t < TL_; ++t) {
        float dtv_n = 0.f, xcv_n = 0.f;
        if (t + 1 < TL_) {
            dtv_n = dtp[(size_t)(t + 1) * DI_];
            xcv_n = b2f(xcp[(size_t)(t + 1) * DI_]);
        }
        const float dx = dtv * xcv;
        #pragma unroll
        for (int qq = 0; qq < 4; ++qq) {
            const float4 bm = *(const float4*)&s_Bm[t * DS_ + qq * 4];
            #pragma unroll
            for (int i = 0; i < 4; ++i) {
                const int s = qq * 4 + i;
                const float bv = (i == 0) ? bm.x : (i == 1) ? bm.y : (i == 2) ? bm.z : bm.w;
                const float dA = __expf(dtv * a[s]);
                P[s] *= dA;
                h[s] = fmaf(dA, h[s], dx * bv);
            }
        }
        dtv = dtv_n; xcv = xcv_n;
    }
    const size_t o0 = (((size_t)b * NCH_ + j) * DS_) * DI_ + d;
    #pragma unroll
    for (int s = 0; s < DS_; ++s) {
        Pc[o0 + (size_t)s * DI_] = P[s];
        Hc[o0 + (size_t)s * DI_] = h[s];
    }
}

__global__ __launch_bounds__(256) void scan_combine(
    const float* __restrict__ Pc, float* __restrict__ Hc)
{
    const size_t idx = (size_t)blockIdx.x * 256 + threadIdx.x;   // over BN*DS*DI
    const size_t b   = idx / (DS_ * DI_);
    const size_t rem = idx % (DS_ * DI_);
    const size_t base   = b * ((size_t)NCH_ * DS_ * DI_) + rem;
    const size_t stride = (size_t)DS_ * DI_;
    float h = 0.f;
    #pragma unroll
    for (int j = 0; j < NCH_; ++j) {
        const size_t o = base + (size_t)j * stride;
        const float P  = Pc[o];
        const float hl = Hc[o];
        Hc[o] = h;                 // incoming state for chunk j
        h = fmaf(P, h, hl);
    }
}

__global__ __launch_bounds__(256) void scan_part2(
    const float* __restrict__ dt, const unsigned short* __restrict__ xcb,
    const unsigned short* __restrict__ gate,     // bf16
    const float* __restrict__ Bm, const float* __restrict__ Cm,
    const float* __restrict__ A, const float* __restrict__ Dp,
    const float* __restrict__ Hin, unsigned short* __restrict__ ygb)
{
    const int tid = threadIdx.x;
    const int d   = blockIdx.x * 256 + tid;
    const int b   = blockIdx.y;
    const int j   = blockIdx.z;
    const int t0  = j * TL_;

    __shared__ float s_Bm[TL_ * DS_];
    __shared__ float s_Cm[TL_ * DS_];
    {
        const float* bsrc = Bm + ((size_t)b * L_ + t0) * DS_;
        const float* csrc = Cm + ((size_t)b * L_ + t0) * DS_;
        s_Bm[tid]       = bsrc[tid];
        s_Bm[256 + tid] = bsrc[256 + tid];
        s_Cm[tid]       = csrc[tid];
        s_Cm[256 + tid] = csrc[256 + tid];
    }
    float a[DS_];
    #pragma unroll
    for (int qq = 0; qq < 4; ++qq)
        *(float4*)&a[qq * 4] = *(const float4*)(A + (size_t)d * DS_ + qq * 4);
    const float dp = Dp[d];

    float h[DS_];
    {
        const size_t o0 = (((size_t)b * NCH_ + j) * DS_) * DI_ + d;
        #pragma unroll
        for (int s = 0; s < DS_; ++s) h[s] = Hin[o0 + (size_t)s * DI_];
    }
    __syncthreads();

    const size_t rbase = ((size_t)b * L_ + t0) * DI_ + d;
    const float* dtp = dt   + rbase;
    const unsigned short* xcp = xcb + rbase;
    const unsigned short* gvp = gate + rbase;
    unsigned short* yp = ygb + rbase;

    float dtv = dtp[0], xcv = b2f(xcp[0]), gv = b2f(gvp[0]);
    #pragma unroll 4
    for (int t = 0; t < TL_; ++t) {
        float dtv_n = 0.f, xcv_n = 0.f, gv_n = 0.f;
        if (t + 1 < TL_) {
            dtv_n = dtp[(size_t)(t + 1) * DI_];
            xcv_n = b2f(xcp[(size_t)(t + 1) * DI_]);
            gv_n  = b2f(gvp[(size_t)(t + 1) * DI_]);
        }
        const float dx = dtv * xcv;
        float y0 = 0.f, y1 = 0.f, y2 = 0.f, y3 = 0.f;
        #pragma unroll
        for (int qq = 0; qq < 4; ++qq) {
            const float4 bm = *(const float4*)&s_Bm[t * DS_ + qq * 4];
            const float4 cm = *(const float4*)&s_Cm[t * DS_ + qq * 4];
            #pragma unroll
            for (int i = 0; i < 4; ++i) {
                const int s = qq * 4 + i;
                const float bv = (i == 0) ? bm.x : (i == 1) ? bm.y : (i == 2) ? bm.z : bm.w;
                const float cv = (i == 0) ? cm.x : (i == 1) ? cm.y : (i == 2) ? cm.z : cm.w;
                const float dA = __expf(dtv * a[s]);
                h[s] = fmaf(dA, h[s], dx * bv);
                if (i == 0) y0 = fmaf(h[s], cv, y0);
                else if (i == 1) y1 = fmaf(h[s], cv, y1);
                else if (i == 2) y2 = fmaf(h[s], cv, y2);
                else y3 = fmaf(h[s], cv, y3);
            }
        }
        float y = (y0 + y1) + (y2 + y3);
        y = fmaf(xcv, dp, y);
        const float r = y * (gv / (1.0f + __expf(-gv)));
        yp[(size_t)t * DI_] = f2b(r);
        dtv = dtv_n; xcv = xcv_n; gv = gv_n;
    }
}

// ---------------------------------------------------------------------------
extern "C" void kernel_launch(void* const* d_in, const int* in_sizes, int n_in,
                              void* d_out, int out_size, void* d_ws, size_t ws_size,
                              hipStream_t stream)
{
    const float* x      = (const float*)d_in[0];
    const float* in_w   = (const float*)d_in[1];
    const float* in_b   = (const float*)d_in[2];
    const float* conv_w = (const float*)d_in[3];
    const float* conv_b = (const float*)d_in[4];
    const float* A      = (const float*)d_in[5];
    const float* Dp     = (const float*)d_in[6];
    const float* B_w    = (const float*)d_in[7];
    const float* B_b    = (const float*)d_in[8];
    const float* C_w    = (const float*)d_in[9];
    const float* C_b    = (const float*)d_in[10];
    const float* dt_w   = (const float*)d_in[11];
    const float* dt_b   = (const float*)d_in[12];
    const float* out_w  = (const float*)d_in[13];
    const float* out_b  = (const float*)d_in[14];
    float* out = (float*)d_out;

    // ---- workspace layout (aliased; peak 64.75 MB) ----
    float* dtb  = (float*)d_ws;                    // [M][DI] fp32, 16MB
    float* Bm   = dtb + (size_t)M_ * DI_;          // [M][16] 128KB
    float* Cm   = Bm  + (size_t)M_ * DS_;          // [M][16] 128KB
    unsigned short* w3  = (unsigned short*)(Cm + (size_t)M_ * DS_); // out_w^T  4MB
    unsigned short* w1  = w3  + (size_t)DM_ * DI_;                  // in_w^T   8MB
    unsigned short* xb  = w1  + (size_t)2 * DI_ * DM_;              // x bf16   4MB
    unsigned short* w2  = xb  + (size_t)M_ * DM_;                   // dtBC^T   8.5MB
    unsigned short* xcb = w2  + (size_t)NBC_ * DI_;                 // xc bf16  8MB
    unsigned short* xzb = xcb + (size_t)M_ * DI_;                   // xz bf16  8MB
    unsigned short* gtb = xzb + (size_t)M_ * DI_;                   // gate bf16 8MB
    unsigned short* ygb = xcb;                     // alias: p2 reads/writes same offsets (safe, see scan_part2)
    float* Pc = (float*)w1;                        // 8MB over w1 (dead after in_proj)
    float* Hc = (float*)xb;                        // 8MB over xb + w2 head (dead after dtBC GEMM)

    // 1) bf16 shadows: x, in_w^T
    cast_bf16<<<(M_ * DM_ / 4 + 255) / 256, 256, 0, stream>>>(x, xb, M_ * DM_);
    transpose_cast<<<dim3(2 * DI_ / 32, DM_ / 32), 256, 0, stream>>>(in_w, w1, DM_, 2 * DI_);

    // 2) [xzb | gtb] = bf16(x @ in_w + in_b)   (M=2048, N=4096, K=1024)
    gemm_mfma<64, 128, 0><<<dim3(2 * DI_ / 128, M_ / 64), 256, 0, stream>>>(
        xb, w1, in_b, nullptr, nullptr,
        nullptr, nullptr, nullptr, xzb, gtb, M_, 2 * DI_, DM_, DI_);

    // 3) depthwise conv + silu (bf16 xcb)
    conv_silu<<<(BN_ * L_ * DI_) / 256, 256, 0, stream>>>(xzb, conv_w, conv_b, xcb);

    // 4) fused dt/B/C weights: w2 = [dt_w | B_w | C_w]^T
    transpose_cast<<<dim3(DI_ / 32, DI_ / 32), 256, 0, stream>>>(dt_w, w2, DI_, DI_);
    bc_pack<<<(32 * 2048) / 256, 256, 0, stream>>>(B_w, C_w, w2);

    // 5) dtb = softplus(xc @ dt_w + dt_b); Bm = xc@B_w+B_b; Cm = xc@C_w+C_b
    gemm_mfma<64, 128, 1><<<dim3(NBC_ / 128, M_ / 64), 256, 0, stream>>>(
        xcb, w2, dt_b, B_b, C_b,
        dtb, Bm, Cm, nullptr, nullptr, M_, NBC_, DI_, NBC_);

    // 6) out_w^T
    transpose_cast<<<dim3(DM_ / 32, DI_ / 32), 256, 0, stream>>>(out_w, w3, DI_, DM_);

    // 7) chunked scan: part1 -> combine -> part2 (writes bf16 ygb)
    scan_part1<<<dim3(DI_ / 256, BN_, NCH_), 256, 0, stream>>>(
        dtb, xcb, Bm, A, Pc, Hc);
    scan_combine<<<(BN_ * DI_ * DS_) / 256, 256, 0, stream>>>(Pc, Hc);
    scan_part2<<<dim3(DI_ / 256, BN_, NCH_), 256, 0, stream>>>(
        dtb, xcb, gtb, Bm, Cm, A, Dp, Hc, ygb);

    // 8) out = yg @ out_w + out_b   (M=2048, N=1024, K=2048)
    gemm_mfma<64, 64, 2><<<dim3(DM_ / 64, M_ / 64), 256, 0, stream>>>(
        ygb, w3, out_b, nullptr, nullptr,
        out, nullptr, nullptr, nullptr, nullptr, M_, DM_, DI_, DM_);
}